// Round 3
// baseline (315.580 us; speedup 1.0000x reference)
//
#include <hip/hip_runtime.h>
#include <hip/hip_bf16.h>
#include <math.h>

typedef __attribute__((ext_vector_type(8))) short short8;
typedef __attribute__((ext_vector_type(4))) float floatx4;
typedef __attribute__((ext_vector_type(4))) unsigned int uintx4;
typedef __attribute__((ext_vector_type(2))) unsigned int uintx2;

__device__ __forceinline__ unsigned short f2bf(float f) {
    unsigned int u = __float_as_uint(f);
    unsigned int r = (u + 0x7fffu + ((u >> 16) & 1u)) >> 16;
    return (unsigned short)r;
}

// single-instruction RNE pack: low16 <- a, high16 <- b
__device__ __forceinline__ unsigned int cvtpk(float a, float b) {
    unsigned int r;
    asm("v_cvt_pk_bf16_f32 %0, %1, %2" : "=v"(r) : "v"(a), "v"(b));
    return r;
}

// swap a's upper 32 lanes with b's lower 32 lanes
__device__ __forceinline__ void permlane32_swap(unsigned int &a, unsigned int &b) {
    asm volatile("v_permlane32_swap_b32 %0, %1" : "+v"(a), "+v"(b));
}
// swap a's odd 16-lane groups with b's even 16-lane groups
__device__ __forceinline__ void permlane16_swap(unsigned int &a, unsigned int &b) {
    asm volatile("v_permlane16_swap_b32 %0, %1" : "+v"(a), "+v"(b));
}

// gelu(u) = u * sigmoid(1.5957691216*u*(1+0.044715*u^2))
// log2e folded: z = -(k1 + k3*u^2)*u, e = 2^z
__device__ __forceinline__ float gelu_f(float u) {
    float u2 = u * u;
    float p = __builtin_fmaf(u2, -0.102943242f, -2.302208184f);
    float z = p * u;
    float e;
    asm("v_exp_f32 %0, %1" : "=v"(e) : "v"(z));
    return u * __builtin_amdgcn_rcpf(1.0f + e);
}

__device__ __forceinline__ floatx4 mfma16(short8 a, short8 b, floatx4 c) {
    return __builtin_amdgcn_mfma_f32_16x16x32_bf16(a, b, c, 0, 0, 0);
}

// ---------------- Phase A ----------------

// 512 blocks: deterministic partial |W| sums (16 partials per tile)
__global__ __launch_bounds__(256) void k_sumabs(const float* __restrict__ W1,
                                                const float* __restrict__ W2,
                                                float* __restrict__ partials) {
    int blk = blockIdx.x;
    bool isW1 = blk < 256;
    const float* W = (isW1 ? W1 : W2) + (long)(isW1 ? blk : blk - 256) * 4096;
    float s = 0.f;
    #pragma unroll
    for (int i = 0; i < 4; i++) {
        floatx4 v = *(const floatx4*)(W + i * 1024 + threadIdx.x * 4);
        s += fabsf(v[0]) + fabsf(v[1]) + fabsf(v[2]) + fabsf(v[3]);
    }
    __shared__ float red[256];
    red[threadIdx.x] = s; __syncthreads();
    for (int st = 128; st > 0; st >>= 1) {
        if (threadIdx.x < st) red[threadIdx.x] += red[threadIdx.x + st];
        __syncthreads();
    }
    if (threadIdx.x == 0) partials[blk] = red[0];
}

// 512 blocks, each owns an 8KB-contiguous OUTPUT slab; quantize via LDS
// transpose tile, dump with coalesced 16B stores (was: 4M scattered 2B stores).
__global__ __launch_bounds__(256) void k_quant(
        const float* __restrict__ W1, const float* __restrict__ W2,
        const float* __restrict__ partials,
        unsigned short* __restrict__ W1qT, unsigned short* __restrict__ W2qT,
        float* ternsum) {
    __shared__ unsigned short Lq[4096];
    __shared__ float red[256];
    int blk = blockIdx.x;
    bool isW1 = blk < 256;
    int rb = isW1 ? blk : blk - 256;
    int t = rb >> 4, slab = rb & 15;
    const float* part = partials + (isW1 ? 0 : 256) + t * 16;
    float ssum = 0.f;
    #pragma unroll
    for (int i = 0; i < 16; i++) ssum += part[i];
    float s = ssum * (1.0f / 65536.0f);
    float thr = 0.7f * s;
    unsigned int us = (unsigned int)f2bf(s);   // bf16(+s); bf16(-s) = us|0x8000
    int tid = threadIdx.x;
    float dsum = 0.f;
    if (isW1) {
        // output W1qT[t] is [512 f][128 d]; slab = 32 f-rows. input W1[t] = [128 d][512 f]
        int f0 = slab * 32;
        int d = tid >> 1, fh = (tid & 1) * 16;
        const float* src = W1 + (long)t * 65536 + d * 512 + f0 + fh;
        #pragma unroll
        for (int i = 0; i < 4; i++) {
            floatx4 w = *(const floatx4*)(src + i * 4);
            #pragma unroll
            for (int r = 0; r < 4; r++) {
                float wv = w[r];
                float aw = fabsf(wv);
                bool big = aw > thr;
                dsum += big ? fabsf(aw - s) : aw;
                unsigned int sign15 = (__float_as_uint(wv) >> 16) & 0x8000u;
                unsigned short q = big ? (unsigned short)(us | sign15) : (unsigned short)0;
                Lq[(fh + i * 4 + r) * 128 + d] = q;   // [32 f][128 d]
            }
        }
    } else {
        // output W2qT[t] is [128 d][512 f]; slab = 8 d-rows. input W2[t] = [512 f][128 d]
        int d0 = slab * 8;
        int f = tid * 2;
        const float* src = W2 + (long)t * 65536 + f * 128 + d0;
        #pragma unroll
        for (int rr = 0; rr < 2; rr++) {
            #pragma unroll
            for (int i = 0; i < 2; i++) {
                floatx4 w = *(const floatx4*)(src + rr * 128 + i * 4);
                #pragma unroll
                for (int r = 0; r < 4; r++) {
                    float wv = w[r];
                    float aw = fabsf(wv);
                    bool big = aw > thr;
                    dsum += big ? fabsf(aw - s) : aw;
                    unsigned int sign15 = (__float_as_uint(wv) >> 16) & 0x8000u;
                    unsigned short q = big ? (unsigned short)(us | sign15) : (unsigned short)0;
                    Lq[(i * 4 + r) * 512 + f + rr] = q;   // [8 d][512 f]
                }
            }
        }
    }
    __syncthreads();
    unsigned short* dst = (isW1 ? W1qT : W2qT) + (long)t * 65536 + slab * 4096;
    const uintx4* Ls = (const uintx4*)Lq;
    uintx4* D4 = (uintx4*)dst;
    D4[tid] = Ls[tid];
    D4[tid + 256] = Ls[tid + 256];
    red[tid] = dsum; __syncthreads();
    for (int st2 = 128; st2 > 0; st2 >>= 1) {
        if (tid < st2) red[tid] += red[tid + st2];
        __syncthreads();
    }
    if (tid == 0) atomicAdd(ternsum, red[0]);
}

// W23qT[t][h][k2] = (W2q[t] @ Wh1)^T, bf16
__global__ __launch_bounds__(256) void k_w23(
        const unsigned short* __restrict__ W2qT, const float* __restrict__ Wh1,
        unsigned short* __restrict__ W23qT) {
    int t = blockIdx.x >> 6, h = blockIdx.x & 63;
    __shared__ float wcol[128];
    if (threadIdx.x < 128) wcol[threadIdx.x] = Wh1[threadIdx.x * 64 + h];
    __syncthreads();
    int k2 = threadIdx.x * 2;
    const unsigned short* w2 = W2qT + (long)t * 65536 + k2;
    float a0 = 0.f, a1 = 0.f;
    #pragma unroll 8
    for (int d = 0; d < 128; d++) {
        unsigned int u = *(const unsigned int*)(w2 + d * 512);
        float w = wcol[d];
        a0 += w * __uint_as_float(u << 16);
        a1 += w * __uint_as_float(u & 0xffff0000u);
    }
    *(unsigned int*)(W23qT + ((long)(t * 64 + h)) * 512 + k2) = cvtpk(a0, a1);
}

__global__ void k_tables(const float* __restrict__ op_embed, const float* __restrict__ W_in,
                         const float* __restrict__ b_in,
                         float* embW, float* Ta, float* Tb, float* Tc) {
    int i = blockIdx.x * 256 + threadIdx.x;
    if (i < 1024) {
        int op = i >> 7, j = i & 127;
        float s = b_in[j];
        #pragma unroll
        for (int k = 0; k < 32; k++) s += op_embed[op * 32 + k] * W_in[k * 128 + j];
        embW[i] = s;
    } else if (i < 1024 + 32768) {
        int r = i - 1024; int a = r >> 7, j = r & 127;
        float s = 0.f;
        #pragma unroll
        for (int bit = 0; bit < 8; bit++) if ((a >> bit) & 1) s += W_in[(32 + bit) * 128 + j];
        Ta[r] = s;
    } else if (i < 33792 + 32768) {
        int r = i - 33792; int b = r >> 7, j = r & 127;
        float s = 0.f;
        #pragma unroll
        for (int bit = 0; bit < 8; bit++) if ((b >> bit) & 1) s += W_in[(40 + bit) * 128 + j];
        Tb[r] = s;
    } else if (i < 66560 + 128) {
        int j = i - 66560; Tc[j] = W_in[48 * 128 + j];
    }
}

__global__ void k_tablesR(const float* __restrict__ embW, const float* __restrict__ Ta,
                          const float* __restrict__ Tb, const float* __restrict__ Tc,
                          const float* __restrict__ Wr,
                          float* embWr, float* TaR, float* TbR, float* TcR) {
    int i = blockIdx.x * 256 + threadIdx.x;
    int row = i >> 4, t = i & 15;
    const float* src; float* dst;
    if (row < 8)        { src = embW + row * 128;        dst = embWr + i; }
    else if (row < 264) { src = Ta + (row - 8) * 128;    dst = TaR + (row - 8) * 16 + t; }
    else if (row < 520) { src = Tb + (row - 264) * 128;  dst = TbR + (row - 264) * 16 + t; }
    else if (row == 520){ src = Tc;                      dst = TcR + t; }
    else return;
    float s = 0.f;
    for (int j = 0; j < 128; j++) s += src[j] * Wr[j * 16 + t];
    *dst = s;
}

// ---------------- Phase B: router + x ----------------

__global__ __launch_bounds__(256) void k_front(
        const int* __restrict__ op_idx, const int* __restrict__ a_in,
        const int* __restrict__ b_in_i, const int* __restrict__ c_in,
        const float* __restrict__ embW, const float* __restrict__ Ta,
        const float* __restrict__ Tb, const float* __restrict__ Tc,
        const float* __restrict__ embWr, const float* __restrict__ TaR,
        const float* __restrict__ TbR, const float* __restrict__ TcR,
        unsigned short* __restrict__ xq, float* __restrict__ gate_out,
        float* psum, int* cnt, float* __restrict__ d_idx) {
    __shared__ float sp[4][16];
    __shared__ int sc[4][16];
    int gid = blockIdx.x * 256 + threadIdx.x;
    int lane = threadIdx.x & 63;
    int j = lane & 15;
    int grpbase = lane & 48;
    float psum_acc = 0.f; int cnt_acc = 0;

    #pragma unroll 1
    for (int it = 0; it < 16; it++) {
        int tok = it * 16384 + (gid >> 4);
        int op = op_idx[tok], a = a_in[tok], b = b_in_i[tok], c = c_in[tok];
        float cf = (float)c;

        float lg = embWr[op * 16 + j] + TaR[a * 16 + j] + TbR[b * 16 + j] + cf * TcR[j];
        float m = lg;
        m = fmaxf(m, __shfl_xor(m, 8, 16));
        m = fmaxf(m, __shfl_xor(m, 4, 16));
        m = fmaxf(m, __shfl_xor(m, 2, 16));
        m = fmaxf(m, __shfl_xor(m, 1, 16));
        float p = __expf(lg - m);
        float s = p;
        s += __shfl_xor(s, 8, 16);
        s += __shfl_xor(s, 4, 16);
        s += __shfl_xor(s, 2, 16);
        s += __shfl_xor(s, 1, 16);
        float g = __builtin_amdgcn_rcpf(s);
        unsigned long long ball = __ballot(lg == m);
        int bi = __ffsll((unsigned long long)((ball >> grpbase) & 0xffffULL)) - 1;
        psum_acc += p * g;
        cnt_acc += (j == bi) ? 1 : 0;
        if (j == 0) { gate_out[tok] = g; d_idx[tok] = (float)bi; }

        int d0 = j * 8;
        const floatx4* E  = (const floatx4*)(embW + op * 128 + d0);
        const floatx4* A4 = (const floatx4*)(Ta + a * 128 + d0);
        const floatx4* B4 = (const floatx4*)(Tb + b * 128 + d0);
        const floatx4* C4 = (const floatx4*)(Tc + d0);
        floatx4 v0 = E[0] + A4[0] + B4[0] + cf * C4[0];
        floatx4 v1 = E[1] + A4[1] + B4[1] + cf * C4[1];
        uintx4 o;
        o[0] = cvtpk(v0[0], v0[1]);
        o[1] = cvtpk(v0[2], v0[3]);
        o[2] = cvtpk(v1[0], v1[1]);
        o[3] = cvtpk(v1[2], v1[3]);
        *(uintx4*)(xq + (long)tok * 128 + d0) = o;
    }

    psum_acc += __shfl_xor(psum_acc, 16);
    psum_acc += __shfl_xor(psum_acc, 32);
    cnt_acc += __shfl_xor(cnt_acc, 16);
    cnt_acc += __shfl_xor(cnt_acc, 32);
    int wv = threadIdx.x >> 6;
    if (lane < 16) { sp[wv][j] = psum_acc; sc[wv][j] = cnt_acc; }
    __syncthreads();
    if (threadIdx.x < 16) {
        int jj = threadIdx.x;
        atomicAdd(&psum[jj], sp[0][jj] + sp[1][jj] + sp[2][jj] + sp[3][jj]);
        atomicAdd(&cnt[jj], sc[0][jj] + sc[1][jj] + sc[2][jj] + sc[3][jj]);
    }
}

// ---------------- scatter (local prefix from cnt) ----------------

__global__ void k_scatter(const float* __restrict__ d_idx, const int* __restrict__ cnt,
                          int* fill, int* __restrict__ bucket) {
    __shared__ int lc[16], lbase[16];
    if (threadIdx.x < 16) lc[threadIdx.x] = 0;
    __syncthreads();
    int offs[16];
    {
        int off = 0;
        #pragma unroll
        for (int tt = 0; tt < 16; tt++) { offs[tt] = off; off += cnt[tt]; }
    }
    int tok = blockIdx.x * 256 + threadIdx.x;
    int t = (int)d_idx[tok];
    int lpos = atomicAdd(&lc[t], 1);
    __syncthreads();
    if (threadIdx.x < 16) lbase[threadIdx.x] = atomicAdd(&fill[threadIdx.x], lc[threadIdx.x]);
    __syncthreads();
    bucket[offs[t] + lbase[t] + lpos] = tok;
}

// ---------------- Phase C: MoE FFN + fused head ----------------
// GEMM1 -> gelu -> in-register permute -> GEMM2 (k-split, rotated h-block
// order so all reg indices are static) -> 16KB round-robin cross-wave
// reduce -> H overlays Ax -> fused head. LDS 36.6KB -> 4 blocks/CU.

__global__ __launch_bounds__(256, 4) void k_ffn(
    const unsigned short* __restrict__ xq, const float* __restrict__ gate,
    const int* __restrict__ bucket, const int* __restrict__ cnt_g,
    const float* __restrict__ psum_g, const float* __restrict__ ternsum_g,
    const unsigned short* __restrict__ W1qT, const unsigned short* __restrict__ W23qT,
    const float* __restrict__ Wh2, const float* __restrict__ bh1,
    const float* __restrict__ bh2,
    float* __restrict__ result, float* __restrict__ d_aux) {

    extern __shared__ __align__(16) unsigned char smem[];
    unsigned short* Ax = (unsigned short*)smem;            // [64][136] bf16 = 17408 B; H f32 [64][68] overlays
    float* Red = (float*)(smem + 17408);                   // 16384 B: 4 slots x [4 mt][64 lane][4]
    int*   toks = (int*)(smem + 33792);                    // 256 B
    float* gats = (float*)(smem + 34048);                  // 256 B
    float* Wh2l = (float*)(smem + 34304);                  // 2048 B
    float* bh2l = (float*)(smem + 36352);                  // 32 B
    float* bh1l = (float*)(smem + 36384);                  // 256 B (end 36640)

    int bid = blockIdx.x;
    // per-block uniform bid -> (tile, chunk) mapping from cnt
    int t = -1, ci = 0, nt = 0, base = 0;
    {
        int coff = 0, off = 0;
        #pragma unroll 1
        for (int tt = 0; tt < 16; tt++) {
            int c = cnt_g[tt];
            int ch = (c + 63) >> 6;
            if (t < 0 && bid < coff + ch) { t = tt; ci = bid - coff; nt = c; base = off + ci * 64; }
            coff += ch; off += c;
        }
    }
    if (t < 0) return;
    int nvalid = nt - ci * 64; if (nvalid > 64) nvalid = 64;

    int tid = threadIdx.x;
    if (tid < 64) {
        int tk = (tid < nvalid) ? bucket[base + tid] : -1;
        toks[tid] = tk;
        gats[tid] = (tk >= 0) ? gate[tk] : 0.0f;
    }
    Wh2l[tid] = Wh2[tid];
    Wh2l[tid + 256] = Wh2[tid + 256];
    if (tid < 8) bh2l[tid] = bh2[tid];
    else if (tid < 72) bh1l[tid - 8] = bh1[tid - 8];
    __syncthreads();

    // stage x rows (gathered, zero-padded)
    #pragma unroll
    for (int it = 0; it < 4; it++) {
        int seg = it * 256 + tid; int r = seg >> 4, sg = seg & 15;
        int tk = toks[r];
        uintx4 v = {0u, 0u, 0u, 0u};
        if (tk >= 0) v = *(const uintx4*)(xq + (long)tk * 128 + sg * 8);
        *(uintx4*)(Ax + r * 136 + sg * 8) = v;
    }
    __syncthreads();

    int lane = tid & 63, dh = tid >> 6;
    int lane15 = lane & 15, lgrp = lane >> 4;

    floatx4 acc3[4][4];   // [i][mt]; i-th slot = h-block (dh+i)&3 (rotated order)
    #pragma unroll
    for (int i = 0; i < 4; i++)
        #pragma unroll
        for (int j = 0; j < 4; j++) acc3[i][j] = (floatx4){0.f, 0.f, 0.f, 0.f};

    const unsigned short* w1p  = W1qT + (long)t * 65536 + (dh * 32 + lane15) * 128 + lgrp * 8;
    const unsigned short* w23p = W23qT + (long)t * 32768 + lane15 * 512 + dh * 32 + lgrp * 8;
    int ho0 = dh * 8192;
    int ho1 = ((dh + 1) & 3) * 8192;
    int ho2 = ((dh + 2) & 3) * 8192;
    int ho3 = ((dh + 3) & 3) * 8192;

    for (int nc = 0; nc < 4; nc++) {
        // GEMM1: A = W1 rows (global), B = Ax (LDS)
        floatx4 acc1[2][4];
        #pragma unroll
        for (int i = 0; i < 2; i++)
            #pragma unroll
            for (int j = 0; j < 4; j++) acc1[i][j] = (floatx4){0.f, 0.f, 0.f, 0.f};

        const unsigned short* w1c = w1p + nc * 16384;
        #pragma unroll
        for (int kk = 0; kk < 4; kk++) {
            short8 af0 = *(const short8*)(w1c + kk * 32);
            short8 af1 = *(const short8*)(w1c + 2048 + kk * 32);
            int ko = kk * 32 + lgrp * 8;
            #pragma unroll
            for (int mt = 0; mt < 4; mt++) {
                short8 bf = *(const short8*)(Ax + (mt * 16 + lane15) * 136 + ko);
                acc1[0][mt] = mfma16(af0, bf, acc1[0][mt]);
                acc1[1][mt] = mfma16(af1, bf, acc1[1][mt]);
            }
        }

        // A-fragments for GEMM2, rotated h-block order
        const unsigned short* w23c = w23p + nc * 128;
        short8 af23_0 = *(const short8*)(w23c + ho0);
        short8 af23_1 = *(const short8*)(w23c + ho1);
        short8 af23_2 = *(const short8*)(w23c + ho2);
        short8 af23_3 = *(const short8*)(w23c + ho3);

        // fuse: gelu -> cvtpk -> lane permute -> B-fragment -> 4 MFMAs (per mt)
        #pragma unroll
        for (int mt = 0; mt < 4; mt++) {
            floatx4 v0 = acc1[0][mt], v1 = acc1[1][mt];
            unsigned int X0 = cvtpk(gelu_f(v0[0]), gelu_f(v0[1]));
            unsigned int X1 = cvtpk(gelu_f(v0[2]), gelu_f(v0[3]));
            unsigned int Y0 = cvtpk(gelu_f(v1[0]), gelu_f(v1[1]));
            unsigned int Y1 = cvtpk(gelu_f(v1[2]), gelu_f(v1[3]));
            permlane32_swap(X0, Y0);
            permlane16_swap(X0, Y0);
            permlane32_swap(X1, Y1);
            permlane16_swap(X1, Y1);
            union { uintx4 u; short8 s; } bu;
            bu.u[0] = X0; bu.u[1] = X1; bu.u[2] = Y0; bu.u[3] = Y1;
            short8 bfrag = bu.s;
            acc3[0][mt] = mfma16(af23_0, bfrag, acc3[0][mt]);
            acc3[1][mt] = mfma16(af23_1, bfrag, acc3[1][mt]);
            acc3[2][mt] = mfma16(af23_2, bfrag, acc3[2][mt]);
            acc3[3][mt] = mfma16(af23_3, bfrag, acc3[3][mt]);
        }
    }

    // ---- cross-wave k-reduction: 3-round round-robin via one 16KB buffer ----
    // acc3[r] = partial for h-block (dh+r)&3 -> round r: write acc3[r] to my
    // slot, partner (dh-r)&3 reads it. All reg indices static.
    floatx4 fin[4];
    #pragma unroll
    for (int mt = 0; mt < 4; mt++) fin[mt] = acc3[0][mt];
    float* myslot = Red + dh * 1024;
    int lofs = lane * 4;
    // round 1
    #pragma unroll
    for (int mt = 0; mt < 4; mt++)
        *(floatx4*)(myslot + mt * 256 + lofs) = acc3[1][mt];
    __syncthreads();
    {
        const float* ps = Red + ((dh + 3) & 3) * 1024;
        #pragma unroll
        for (int mt = 0; mt < 4; mt++)
            fin[mt] += *(const floatx4*)(ps + mt * 256 + lofs);
    }
    __syncthreads();
    // round 2
    #pragma unroll
    for (int mt = 0; mt < 4; mt++)
        *(floatx4*)(myslot + mt * 256 + lofs) = acc3[2][mt];
    __syncthreads();
    {
        const float* ps = Red + ((dh + 2) & 3) * 1024;
        #pragma unroll
        for (int mt = 0; mt < 4; mt++)
            fin[mt] += *(const floatx4*)(ps + mt * 256 + lofs);
    }
    __syncthreads();
    // round 3
    #pragma unroll
    for (int mt = 0; mt < 4; mt++)
        *(floatx4*)(myslot + mt * 256 + lofs) = acc3[3][mt];
    __syncthreads();
    {
        const float* ps = Red + ((dh + 1) & 3) * 1024;
        #pragma unroll
        for (int mt = 0; mt < 4; mt++)
            fin[mt] += *(const floatx4*)(ps + mt * 256 + lofs);
    }

    // H overlays Ax (dead after nc loop; ordered by the reduce barriers)
    float* H = (float*)Ax;                   // [64 m][68] f32 = 17408 B
    int hb = dh * 16 + lgrp * 4;
    floatx4 b4 = *(const floatx4*)(bh1l + hb);
    #pragma unroll
    for (int mt = 0; mt < 4; mt++) {
        int m = mt * 16 + lane15;
        float gm = gats[m];
        floatx4 v;
        v[0] = fmaxf(fin[mt][0] * gm + b4[0], 0.f);
        v[1] = fmaxf(fin[mt][1] * gm + b4[1], 0.f);
        v[2] = fmaxf(fin[mt][2] * gm + b4[2], 0.f);
        v[3] = fmaxf(fin[mt][3] * gm + b4[3], 0.f);
        *(floatx4*)(H + m * 68 + hb) = v;
    }
    __syncthreads();                         // H complete

    int mloc = tid >> 2, c0 = (tid & 3) * 2;
    int tk = toks[mloc];
    float z0 = bh2l[c0], z1 = bh2l[c0 + 1];
    const floatx4* Hr4 = (const floatx4*)(H + mloc * 68);
    #pragma unroll
    for (int h4 = 0; h4 < 16; h4++) {
        floatx4 hv = Hr4[h4];
        #pragma unroll
        for (int r = 0; r < 4; r++) {
            int h = h4 * 4 + r;
            z0 += hv[r] * Wh2l[h * 8 + c0];
            z1 += hv[r] * Wh2l[h * 8 + c0 + 1];
        }
    }
    if (tk >= 0) {
        float2 rr;
        rr.x = __builtin_amdgcn_rcpf(1.0f + __expf(-z0));
        rr.y = __builtin_amdgcn_rcpf(1.0f + __expf(-z1));
        *(float2*)(result + (long)tk * 8 + c0) = rr;
    }

    // aux loss (block 0 only)
    if (bid == 0 && tid == 0) {
        const float Bf = 262144.0f;
        float tern = ternsum_g[0] * (1.0f / 1048576.0f);
        float sp = 0.f; float cp[4] = {0.f, 0.f, 0.f, 0.f};
        for (int tt = 0; tt < 16; tt++) {
            float frac = (float)cnt_g[tt] / Bf, mp = psum_g[tt] / Bf;
            sp += frac * mp; cp[tt >> 2] += mp;
        }
        float dv = 0.f;
        for (int cc = 0; cc < 4; cc++) dv += cp[cc] * logf(cp[cc] + 1e-9f);
        d_aux[0] = 0.01f * tern + 0.005f * (16.0f * sp) + 0.01f * dv;
    }
}

// ---------------- launch ----------------

extern "C" void kernel_launch(void* const* d_in, const int* in_sizes, int n_in,
                              void* d_out, int out_size, void* d_ws, size_t ws_size,
                              hipStream_t stream) {
    const int* op_idx = (const int*)d_in[0];
    const int* a_in   = (const int*)d_in[1];
    const int* b_in_i = (const int*)d_in[2];
    const int* c_in   = (const int*)d_in[3];
    const float* op_embed = (const float*)d_in[4];
    const float* W_in  = (const float*)d_in[5];
    const float* b_in  = (const float*)d_in[6];
    const float* Wr    = (const float*)d_in[7];
    const float* W1    = (const float*)d_in[8];
    const float* W2    = (const float*)d_in[9];
    const float* Wh1   = (const float*)d_in[10];
    const float* bh1   = (const float*)d_in[11];
    const float* Wh2   = (const float*)d_in[12];
    const float* bh2   = (const float*)d_in[13];

    const long B = in_sizes[0];  // 262144
    float* result = (float*)d_out;
    float* d_idx  = (float*)d_out + B * 8;
    float* d_aux  = (float*)d_out + B * 9;

    unsigned char* ws = (unsigned char*)d_ws;
    unsigned short* xq    = (unsigned short*)(ws + 0);            // 64 MB
    unsigned short* W1qT  = (unsigned short*)(ws + 67108864);     // 2 MB
    unsigned short* W2qT  = (unsigned short*)(ws + 69206016);     // 2 MB
    unsigned short* W23qT = (unsigned short*)(ws + 71303168);     // 1 MB
    float* gate  = (float*)(ws + 72351744);                       // 1 MB
    int*   bucket= (int*)  (ws + 73400320);                       // 1 MB
    float* Ta    = (float*)(ws + 74448896);                       // 128 KB
    float* Tb    = (float*)(ws + 74579968);                       // 128 KB
    float* embW  = (float*)(ws + 74711040);                       // 4 KB
    float* Tc    = (float*)(ws + 74715136);                       // 512 B
    float* TaR   = (float*)(ws + 74715648);                       // 16 KB
    float* TbR   = (float*)(ws + 74732032);                       // 16 KB
    float* embWr = (float*)(ws + 74748416);                       // 512 B
    float* TcR   = (float*)(ws + 74748928);                       // 64 B
    float* partials = (float*)(ws + 74748992);                    // 2 KB
    unsigned char* acc = ws + 74751040;
    float* ternsum = (float*)(acc + 0);
    float* psum    = (float*)(acc + 64);
    int*   cnt     = (int*)(acc + 128);
    int*   fill    = (int*)(acc + 192);

    hipMemsetAsync(acc, 0, 256, stream);

    k_sumabs<<<512, 256, 0, stream>>>(W1, W2, partials);
    k_quant<<<512, 256, 0, stream>>>(W1, W2, partials, W1qT, W2qT, ternsum);
    k_tables<<<261, 256, 0, stream>>>(op_embed, W_in, b_in, embW, Ta, Tb, Tc);
    k_tablesR<<<33, 256, 0, stream>>>(embW, Ta, Tb, Tc, Wr, embWr, TaR, TbR, TcR);
    k_front<<<1024, 256, 0, stream>>>(op_idx, a_in, b_in_i, c_in,
                                      embW, Ta, Tb, Tc, embWr, TaR, TbR, TcR,
                                      xq, gate, psum, cnt, d_idx);
    k_w23<<<1024, 256, 0, stream>>>(W2qT, Wh1, W23qT);
    k_scatter<<<(int)(B / 256), 256, 0, stream>>>(d_idx, cnt, fill, bucket);
    k_ffn<<<4112, 256, 36640, stream>>>(xq, gate, bucket, cnt, psum, ternsum,
                                        W1qT, W23qT, Wh2, bh1, bh2, result, d_aux);
}

// Round 4
// 266.583 us; speedup vs baseline: 1.1838x; 1.1838x over previous
//
#include <hip/hip_runtime.h>
#include <hip/hip_bf16.h>
#include <math.h>

typedef __attribute__((ext_vector_type(8))) short short8;
typedef __attribute__((ext_vector_type(4))) float floatx4;
typedef __attribute__((ext_vector_type(4))) unsigned int uintx4;
typedef __attribute__((ext_vector_type(2))) unsigned int uintx2;

__device__ __forceinline__ unsigned short f2bf(float f) {
    unsigned int u = __float_as_uint(f);
    unsigned int r = (u + 0x7fffu + ((u >> 16) & 1u)) >> 16;
    return (unsigned short)r;
}

// single-instruction RNE pack: low16 <- a, high16 <- b
__device__ __forceinline__ unsigned int cvtpk(float a, float b) {
    unsigned int r;
    asm("v_cvt_pk_bf16_f32 %0, %1, %2" : "=v"(r) : "v"(a), "v"(b));
    return r;
}

// swap a's upper 32 lanes with b's lower 32 lanes
__device__ __forceinline__ void permlane32_swap(unsigned int &a, unsigned int &b) {
    asm volatile("v_permlane32_swap_b32 %0, %1" : "+v"(a), "+v"(b));
}
// swap a's odd 16-lane groups with b's even 16-lane groups
__device__ __forceinline__ void permlane16_swap(unsigned int &a, unsigned int &b) {
    asm volatile("v_permlane16_swap_b32 %0, %1" : "+v"(a), "+v"(b));
}

// gelu(u) = u * sigmoid(1.5957691216*u*(1+0.044715*u^2))
// log2e folded: z = -(k1 + k3*u^2)*u, e = 2^z
__device__ __forceinline__ float gelu_f(float u) {
    float u2 = u * u;
    float p = __builtin_fmaf(u2, -0.102943242f, -2.302208184f);
    float z = p * u;
    float e;
    asm("v_exp_f32 %0, %1" : "=v"(e) : "v"(z));
    return u * __builtin_amdgcn_rcpf(1.0f + e);
}

__device__ __forceinline__ floatx4 mfma16(short8 a, short8 b, floatx4 c) {
    return __builtin_amdgcn_mfma_f32_16x16x32_bf16(a, b, c, 0, 0, 0);
}

// ---------------- Stage 1: |W| partial sums  ∪  input tables ----------------
// blocks [0,512): sumabs; blocks [512,773): tables

__global__ __launch_bounds__(256) void k_prep1(
        const float* __restrict__ W1, const float* __restrict__ W2,
        float* __restrict__ partials,
        const float* __restrict__ op_embed, const float* __restrict__ W_in,
        const float* __restrict__ b_in,
        float* embW, float* Ta, float* Tb, float* Tc) {
    __shared__ float red[256];
    int bid = blockIdx.x;
    if (bid < 512) {
        bool isW1 = bid < 256;
        const float* W = (isW1 ? W1 : W2) + (long)(isW1 ? bid : bid - 256) * 4096;
        float s = 0.f;
        #pragma unroll
        for (int i = 0; i < 4; i++) {
            floatx4 v = *(const floatx4*)(W + i * 1024 + threadIdx.x * 4);
            s += fabsf(v[0]) + fabsf(v[1]) + fabsf(v[2]) + fabsf(v[3]);
        }
        red[threadIdx.x] = s; __syncthreads();
        for (int st = 128; st > 0; st >>= 1) {
            if (threadIdx.x < st) red[threadIdx.x] += red[threadIdx.x + st];
            __syncthreads();
        }
        if (threadIdx.x == 0) partials[bid] = red[0];
    } else {
        int i = (bid - 512) * 256 + threadIdx.x;
        if (i < 1024) {
            int op = i >> 7, j = i & 127;
            float s = b_in[j];
            #pragma unroll
            for (int k = 0; k < 32; k++) s += op_embed[op * 32 + k] * W_in[k * 128 + j];
            embW[i] = s;
        } else if (i < 1024 + 32768) {
            int r = i - 1024; int a = r >> 7, j = r & 127;
            float s = 0.f;
            #pragma unroll
            for (int bit = 0; bit < 8; bit++) if ((a >> bit) & 1) s += W_in[(32 + bit) * 128 + j];
            Ta[r] = s;
        } else if (i < 33792 + 32768) {
            int r = i - 33792; int b = r >> 7, j = r & 127;
            float s = 0.f;
            #pragma unroll
            for (int bit = 0; bit < 8; bit++) if ((b >> bit) & 1) s += W_in[(40 + bit) * 128 + j];
            Tb[r] = s;
        } else if (i < 66560 + 128) {
            int j = i - 66560; Tc[j] = W_in[48 * 128 + j];
        }
    }
}

// ---------------- Stage 2: quantize  ∪  router tables ----------------
// blocks [0,512): quant (coalesced-output via LDS transpose); [512,545): tablesR

__global__ __launch_bounds__(256) void k_prep2(
        const float* __restrict__ W1, const float* __restrict__ W2,
        const float* __restrict__ partials,
        unsigned short* __restrict__ W1qT, unsigned short* __restrict__ W2qT,
        float* ternsum,
        const float* __restrict__ embW, const float* __restrict__ Ta,
        const float* __restrict__ Tb, const float* __restrict__ Tc,
        const float* __restrict__ Wr,
        float* embWr, float* TaR, float* TbR, float* TcR) {
    __shared__ unsigned short Lq[4096];
    __shared__ float red[256];
    int blk = blockIdx.x;
    if (blk >= 512) {
        int i = (blk - 512) * 256 + threadIdx.x;
        int row = i >> 4, t = i & 15;
        const float* src; float* dst;
        if (row < 8)        { src = embW + row * 128;        dst = embWr + i; }
        else if (row < 264) { src = Ta + (row - 8) * 128;    dst = TaR + (row - 8) * 16 + t; }
        else if (row < 520) { src = Tb + (row - 264) * 128;  dst = TbR + (row - 264) * 16 + t; }
        else if (row == 520){ src = Tc;                      dst = TcR + t; }
        else return;
        float s = 0.f;
        for (int j = 0; j < 128; j++) s += src[j] * Wr[j * 16 + t];
        *dst = s;
        return;
    }
    bool isW1 = blk < 256;
    int rb = isW1 ? blk : blk - 256;
    int t = rb >> 4, slab = rb & 15;
    const float* part = partials + (isW1 ? 0 : 256) + t * 16;
    float ssum = 0.f;
    #pragma unroll
    for (int i = 0; i < 16; i++) ssum += part[i];
    float s = ssum * (1.0f / 65536.0f);
    float thr = 0.7f * s;
    unsigned int us = (unsigned int)f2bf(s);   // bf16(+s); bf16(-s) = us|0x8000
    int tid = threadIdx.x;
    float dsum = 0.f;
    if (isW1) {
        // output W1qT[t] is [512 f][128 d]; slab = 32 f-rows. input W1[t] = [128 d][512 f]
        int f0 = slab * 32;
        int d = tid >> 1, fh = (tid & 1) * 16;
        const float* src = W1 + (long)t * 65536 + d * 512 + f0 + fh;
        #pragma unroll
        for (int i = 0; i < 4; i++) {
            floatx4 w = *(const floatx4*)(src + i * 4);
            #pragma unroll
            for (int r = 0; r < 4; r++) {
                float wv = w[r];
                float aw = fabsf(wv);
                bool big = aw > thr;
                dsum += big ? fabsf(aw - s) : aw;
                unsigned int sign15 = (__float_as_uint(wv) >> 16) & 0x8000u;
                unsigned short q = big ? (unsigned short)(us | sign15) : (unsigned short)0;
                Lq[(fh + i * 4 + r) * 128 + d] = q;   // [32 f][128 d]
            }
        }
    } else {
        // output W2qT[t] is [128 d][512 f]; slab = 8 d-rows. input W2[t] = [512 f][128 d]
        int d0 = slab * 8;
        int f = tid * 2;
        const float* src = W2 + (long)t * 65536 + f * 128 + d0;
        #pragma unroll
        for (int rr = 0; rr < 2; rr++) {
            #pragma unroll
            for (int i = 0; i < 2; i++) {
                floatx4 w = *(const floatx4*)(src + rr * 128 + i * 4);
                #pragma unroll
                for (int r = 0; r < 4; r++) {
                    float wv = w[r];
                    float aw = fabsf(wv);
                    bool big = aw > thr;
                    dsum += big ? fabsf(aw - s) : aw;
                    unsigned int sign15 = (__float_as_uint(wv) >> 16) & 0x8000u;
                    unsigned short q = big ? (unsigned short)(us | sign15) : (unsigned short)0;
                    Lq[(i * 4 + r) * 512 + f + rr] = q;   // [8 d][512 f]
                }
            }
        }
    }
    __syncthreads();
    unsigned short* dst = (isW1 ? W1qT : W2qT) + (long)t * 65536 + slab * 4096;
    const uintx4* Ls = (const uintx4*)Lq;
    uintx4* D4 = (uintx4*)dst;
    D4[tid] = Ls[tid];
    D4[tid + 256] = Ls[tid + 256];
    red[tid] = dsum; __syncthreads();
    for (int st2 = 128; st2 > 0; st2 >>= 1) {
        if (tid < st2) red[tid] += red[tid + st2];
        __syncthreads();
    }
    if (tid == 0) atomicAdd(ternsum, red[0]);
}

// ---------------- Stage 3: router/x front  ∪  W23 precompute ----------------
// blocks [0,1024): front; blocks [1024,2048): w23

__global__ __launch_bounds__(256) void k_main3(
        const int* __restrict__ op_idx, const int* __restrict__ a_in,
        const int* __restrict__ b_in_i, const int* __restrict__ c_in,
        const float* __restrict__ embW, const float* __restrict__ Ta,
        const float* __restrict__ Tb, const float* __restrict__ Tc,
        const float* __restrict__ embWr, const float* __restrict__ TaR,
        const float* __restrict__ TbR, const float* __restrict__ TcR,
        unsigned short* __restrict__ xq, float* __restrict__ gate_out,
        float* psum, int* cnt, float* __restrict__ d_idx,
        const unsigned short* __restrict__ W2qT, const float* __restrict__ Wh1,
        unsigned short* __restrict__ W23qT) {
    __shared__ float sp[4][16];
    __shared__ int sc[4][16];
    __shared__ float wcol[128];

    if (blockIdx.x >= 1024) {
        int b2 = blockIdx.x - 1024;
        int t = b2 >> 6, h = b2 & 63;
        if (threadIdx.x < 128) wcol[threadIdx.x] = Wh1[threadIdx.x * 64 + h];
        __syncthreads();
        int k2 = threadIdx.x * 2;
        const unsigned short* w2 = W2qT + (long)t * 65536 + k2;
        float a0 = 0.f, a1 = 0.f;
        #pragma unroll 8
        for (int d = 0; d < 128; d++) {
            unsigned int u = *(const unsigned int*)(w2 + d * 512);
            float w = wcol[d];
            a0 += w * __uint_as_float(u << 16);
            a1 += w * __uint_as_float(u & 0xffff0000u);
        }
        *(unsigned int*)(W23qT + ((long)(t * 64 + h)) * 512 + k2) = cvtpk(a0, a1);
        return;
    }

    int gid = blockIdx.x * 256 + threadIdx.x;
    int lane = threadIdx.x & 63;
    int j = lane & 15;
    int grpbase = lane & 48;
    float psum_acc = 0.f; int cnt_acc = 0;

    #pragma unroll 1
    for (int it = 0; it < 16; it++) {
        int tok = it * 16384 + (gid >> 4);
        int op = op_idx[tok], a = a_in[tok], b = b_in_i[tok], c = c_in[tok];
        float cf = (float)c;

        float lg = embWr[op * 16 + j] + TaR[a * 16 + j] + TbR[b * 16 + j] + cf * TcR[j];
        float m = lg;
        m = fmaxf(m, __shfl_xor(m, 8, 16));
        m = fmaxf(m, __shfl_xor(m, 4, 16));
        m = fmaxf(m, __shfl_xor(m, 2, 16));
        m = fmaxf(m, __shfl_xor(m, 1, 16));
        float p = __expf(lg - m);
        float s = p;
        s += __shfl_xor(s, 8, 16);
        s += __shfl_xor(s, 4, 16);
        s += __shfl_xor(s, 2, 16);
        s += __shfl_xor(s, 1, 16);
        float g = __builtin_amdgcn_rcpf(s);
        unsigned long long ball = __ballot(lg == m);
        int bi = __ffsll((unsigned long long)((ball >> grpbase) & 0xffffULL)) - 1;
        psum_acc += p * g;
        cnt_acc += (j == bi) ? 1 : 0;
        if (j == 0) { gate_out[tok] = g; d_idx[tok] = (float)bi; }

        int d0 = j * 8;
        const floatx4* E  = (const floatx4*)(embW + op * 128 + d0);
        const floatx4* A4 = (const floatx4*)(Ta + a * 128 + d0);
        const floatx4* B4 = (const floatx4*)(Tb + b * 128 + d0);
        const floatx4* C4 = (const floatx4*)(Tc + d0);
        floatx4 v0 = E[0] + A4[0] + B4[0] + cf * C4[0];
        floatx4 v1 = E[1] + A4[1] + B4[1] + cf * C4[1];
        uintx4 o;
        o[0] = cvtpk(v0[0], v0[1]);
        o[1] = cvtpk(v0[2], v0[3]);
        o[2] = cvtpk(v1[0], v1[1]);
        o[3] = cvtpk(v1[2], v1[3]);
        *(uintx4*)(xq + (long)tok * 128 + d0) = o;
    }

    psum_acc += __shfl_xor(psum_acc, 16);
    psum_acc += __shfl_xor(psum_acc, 32);
    cnt_acc += __shfl_xor(cnt_acc, 16);
    cnt_acc += __shfl_xor(cnt_acc, 32);
    int wv = threadIdx.x >> 6;
    if (lane < 16) { sp[wv][j] = psum_acc; sc[wv][j] = cnt_acc; }
    __syncthreads();
    if (threadIdx.x < 16) {
        int jj = threadIdx.x;
        atomicAdd(&psum[jj], sp[0][jj] + sp[1][jj] + sp[2][jj] + sp[3][jj]);
        atomicAdd(&cnt[jj], sc[0][jj] + sc[1][jj] + sc[2][jj] + sc[3][jj]);
    }
}

// ---------------- scatter (local prefix from cnt) ----------------

__global__ void k_scatter(const float* __restrict__ d_idx, const int* __restrict__ cnt,
                          int* fill, int* __restrict__ bucket) {
    __shared__ int lc[16], lbase[16];
    if (threadIdx.x < 16) lc[threadIdx.x] = 0;
    __syncthreads();
    int offs[16];
    {
        int off = 0;
        #pragma unroll
        for (int tt = 0; tt < 16; tt++) { offs[tt] = off; off += cnt[tt]; }
    }
    int tok = blockIdx.x * 256 + threadIdx.x;
    int t = (int)d_idx[tok];
    int lpos = atomicAdd(&lc[t], 1);
    __syncthreads();
    if (threadIdx.x < 16) lbase[threadIdx.x] = atomicAdd(&fill[threadIdx.x], lc[threadIdx.x]);
    __syncthreads();
    bucket[offs[t] + lbase[t] + lpos] = tok;
}

// ---------------- Phase C: MoE FFN + fused head ----------------
// GEMM1 -> gelu -> in-register permute -> GEMM2 (k-split, rotated h-block
// order so all reg indices are static) -> 16KB round-robin cross-wave
// reduce -> H overlays Ax -> fused head.
// launch_bounds(256,3): (256,4) caps regs at 128 and SPILLS (R3: 172MB
// scratch writes, 5x hbm traffic). k-split forces 64-reg acc3 + 32-reg acc1.

__global__ __launch_bounds__(256, 3) void k_ffn(
    const unsigned short* __restrict__ xq, const float* __restrict__ gate,
    const int* __restrict__ bucket, const int* __restrict__ cnt_g,
    const float* __restrict__ psum_g, const float* __restrict__ ternsum_g,
    const unsigned short* __restrict__ W1qT, const unsigned short* __restrict__ W23qT,
    const float* __restrict__ Wh2, const float* __restrict__ bh1,
    const float* __restrict__ bh2,
    float* __restrict__ result, float* __restrict__ d_aux) {

    extern __shared__ __align__(16) unsigned char smem[];
    unsigned short* Ax = (unsigned short*)smem;            // [64][136] bf16 = 17408 B; H f32 [64][68] overlays
    float* Red = (float*)(smem + 17408);                   // 16384 B: 4 slots x [4 mt][64 lane][4]
    int*   toks = (int*)(smem + 33792);                    // 256 B
    float* gats = (float*)(smem + 34048);                  // 256 B
    float* Wh2l = (float*)(smem + 34304);                  // 2048 B
    float* bh2l = (float*)(smem + 36352);                  // 32 B
    float* bh1l = (float*)(smem + 36384);                  // 256 B (end 36640)

    int bid = blockIdx.x;
    // per-block uniform bid -> (tile, chunk) mapping from cnt
    int t = -1, ci = 0, nt = 0, base = 0;
    {
        int coff = 0, off = 0;
        #pragma unroll 1
        for (int tt = 0; tt < 16; tt++) {
            int c = cnt_g[tt];
            int ch = (c + 63) >> 6;
            if (t < 0 && bid < coff + ch) { t = tt; ci = bid - coff; nt = c; base = off + ci * 64; }
            coff += ch; off += c;
        }
    }
    if (t < 0) return;
    int nvalid = nt - ci * 64; if (nvalid > 64) nvalid = 64;

    int tid = threadIdx.x;
    if (tid < 64) {
        int tk = (tid < nvalid) ? bucket[base + tid] : -1;
        toks[tid] = tk;
        gats[tid] = (tk >= 0) ? gate[tk] : 0.0f;
    }
    Wh2l[tid] = Wh2[tid];
    Wh2l[tid + 256] = Wh2[tid + 256];
    if (tid < 8) bh2l[tid] = bh2[tid];
    else if (tid < 72) bh1l[tid - 8] = bh1[tid - 8];
    __syncthreads();

    // stage x rows (gathered, zero-padded)
    #pragma unroll
    for (int it = 0; it < 4; it++) {
        int seg = it * 256 + tid; int r = seg >> 4, sg = seg & 15;
        int tk = toks[r];
        uintx4 v = {0u, 0u, 0u, 0u};
        if (tk >= 0) v = *(const uintx4*)(xq + (long)tk * 128 + sg * 8);
        *(uintx4*)(Ax + r * 136 + sg * 8) = v;
    }
    __syncthreads();

    int lane = tid & 63, dh = tid >> 6;
    int lane15 = lane & 15, lgrp = lane >> 4;

    floatx4 acc3[4][4];   // [i][mt]; i-th slot = h-block (dh+i)&3 (rotated order)
    #pragma unroll
    for (int i = 0; i < 4; i++)
        #pragma unroll
        for (int j = 0; j < 4; j++) acc3[i][j] = (floatx4){0.f, 0.f, 0.f, 0.f};

    const unsigned short* w1p  = W1qT + (long)t * 65536 + (dh * 32 + lane15) * 128 + lgrp * 8;
    const unsigned short* w23p = W23qT + (long)t * 32768 + lane15 * 512 + dh * 32 + lgrp * 8;
    int ho0 = dh * 8192;
    int ho1 = ((dh + 1) & 3) * 8192;
    int ho2 = ((dh + 2) & 3) * 8192;
    int ho3 = ((dh + 3) & 3) * 8192;

    for (int nc = 0; nc < 4; nc++) {
        // GEMM1: A = W1 rows (global), B = Ax (LDS)
        floatx4 acc1[2][4];
        #pragma unroll
        for (int i = 0; i < 2; i++)
            #pragma unroll
            for (int j = 0; j < 4; j++) acc1[i][j] = (floatx4){0.f, 0.f, 0.f, 0.f};

        const unsigned short* w1c = w1p + nc * 16384;
        #pragma unroll
        for (int kk = 0; kk < 4; kk++) {
            short8 af0 = *(const short8*)(w1c + kk * 32);
            short8 af1 = *(const short8*)(w1c + 2048 + kk * 32);
            int ko = kk * 32 + lgrp * 8;
            #pragma unroll
            for (int mt = 0; mt < 4; mt++) {
                short8 bf = *(const short8*)(Ax + (mt * 16 + lane15) * 136 + ko);
                acc1[0][mt] = mfma16(af0, bf, acc1[0][mt]);
                acc1[1][mt] = mfma16(af1, bf, acc1[1][mt]);
            }
        }

        // A-fragments for GEMM2, rotated h-block order
        const unsigned short* w23c = w23p + nc * 128;
        short8 af23_0 = *(const short8*)(w23c + ho0);
        short8 af23_1 = *(const short8*)(w23c + ho1);
        short8 af23_2 = *(const short8*)(w23c + ho2);
        short8 af23_3 = *(const short8*)(w23c + ho3);

        // fuse: gelu -> cvtpk -> lane permute -> B-fragment -> 4 MFMAs (per mt)
        #pragma unroll
        for (int mt = 0; mt < 4; mt++) {
            floatx4 v0 = acc1[0][mt], v1 = acc1[1][mt];
            unsigned int X0 = cvtpk(gelu_f(v0[0]), gelu_f(v0[1]));
            unsigned int X1 = cvtpk(gelu_f(v0[2]), gelu_f(v0[3]));
            unsigned int Y0 = cvtpk(gelu_f(v1[0]), gelu_f(v1[1]));
            unsigned int Y1 = cvtpk(gelu_f(v1[2]), gelu_f(v1[3]));
            permlane32_swap(X0, Y0);
            permlane16_swap(X0, Y0);
            permlane32_swap(X1, Y1);
            permlane16_swap(X1, Y1);
            union { uintx4 u; short8 s; } bu;
            bu.u[0] = X0; bu.u[1] = X1; bu.u[2] = Y0; bu.u[3] = Y1;
            short8 bfrag = bu.s;
            acc3[0][mt] = mfma16(af23_0, bfrag, acc3[0][mt]);
            acc3[1][mt] = mfma16(af23_1, bfrag, acc3[1][mt]);
            acc3[2][mt] = mfma16(af23_2, bfrag, acc3[2][mt]);
            acc3[3][mt] = mfma16(af23_3, bfrag, acc3[3][mt]);
        }
    }

    // ---- cross-wave k-reduction: 3-round round-robin via one 16KB buffer ----
    // acc3[r] = partial for h-block (dh+r)&3 -> round r: write acc3[r] to my
    // slot, partner (dh-r)&3 reads it. All reg indices static.
    floatx4 fin[4];
    #pragma unroll
    for (int mt = 0; mt < 4; mt++) fin[mt] = acc3[0][mt];
    float* myslot = Red + dh * 1024;
    int lofs = lane * 4;
    // round 1
    #pragma unroll
    for (int mt = 0; mt < 4; mt++)
        *(floatx4*)(myslot + mt * 256 + lofs) = acc3[1][mt];
    __syncthreads();
    {
        const float* ps = Red + ((dh + 3) & 3) * 1024;
        #pragma unroll
        for (int mt = 0; mt < 4; mt++)
            fin[mt] += *(const floatx4*)(ps + mt * 256 + lofs);
    }
    __syncthreads();
    // round 2
    #pragma unroll
    for (int mt = 0; mt < 4; mt++)
        *(floatx4*)(myslot + mt * 256 + lofs) = acc3[2][mt];
    __syncthreads();
    {
        const float* ps = Red + ((dh + 2) & 3) * 1024;
        #pragma unroll
        for (int mt = 0; mt < 4; mt++)
            fin[mt] += *(const floatx4*)(ps + mt * 256 + lofs);
    }
    __syncthreads();
    // round 3
    #pragma unroll
    for (int mt = 0; mt < 4; mt++)
        *(floatx4*)(myslot + mt * 256 + lofs) = acc3[3][mt];
    __syncthreads();
    {
        const float* ps = Red + ((dh + 1) & 3) * 1024;
        #pragma unroll
        for (int mt = 0; mt < 4; mt++)
            fin[mt] += *(const floatx4*)(ps + mt * 256 + lofs);
    }

    // H overlays Ax (dead after nc loop; ordered by the reduce barriers)
    float* H = (float*)Ax;                   // [64 m][68] f32 = 17408 B
    int hb = dh * 16 + lgrp * 4;
    floatx4 b4 = *(const floatx4*)(bh1l + hb);
    #pragma unroll
    for (int mt = 0; mt < 4; mt++) {
        int m = mt * 16 + lane15;
        float gm = gats[m];
        floatx4 v;
        v[0] = fmaxf(fin[mt][0] * gm + b4[0], 0.f);
        v[1] = fmaxf(fin[mt][1] * gm + b4[1], 0.f);
        v[2] = fmaxf(fin[mt][2] * gm + b4[2], 0.f);
        v[3] = fmaxf(fin[mt][3] * gm + b4[3], 0.f);
        *(floatx4*)(H + m * 68 + hb) = v;
    }
    __syncthreads();                         // H complete

    int mloc = tid >> 2, c0 = (tid & 3) * 2;
    int tk = toks[mloc];
    float z0 = bh2l[c0], z1 = bh2l[c0 + 1];
    const floatx4* Hr4 = (const floatx4*)(H + mloc * 68);
    #pragma unroll
    for (int h4 = 0; h4 < 16; h4++) {
        floatx4 hv = Hr4[h4];
        #pragma unroll
        for (int r = 0; r < 4; r++) {
            int h = h4 * 4 + r;
            z0 += hv[r] * Wh2l[h * 8 + c0];
            z1 += hv[r] * Wh2l[h * 8 + c0 + 1];
        }
    }
    if (tk >= 0) {
        float2 rr;
        rr.x = __builtin_amdgcn_rcpf(1.0f + __expf(-z0));
        rr.y = __builtin_amdgcn_rcpf(1.0f + __expf(-z1));
        *(float2*)(result + (long)tk * 8 + c0) = rr;
    }

    // aux loss (block 0 only)
    if (bid == 0 && tid == 0) {
        const float Bf = 262144.0f;
        float tern = ternsum_g[0] * (1.0f / 1048576.0f);
        float sp = 0.f; float cp[4] = {0.f, 0.f, 0.f, 0.f};
        for (int tt = 0; tt < 16; tt++) {
            float frac = (float)cnt_g[tt] / Bf, mp = psum_g[tt] / Bf;
            sp += frac * mp; cp[tt >> 2] += mp;
        }
        float dv = 0.f;
        for (int cc = 0; cc < 4; cc++) dv += cp[cc] * logf(cp[cc] + 1e-9f);
        d_aux[0] = 0.01f * tern + 0.005f * (16.0f * sp) + 0.01f * dv;
    }
}

// ---------------- launch ----------------

extern "C" void kernel_launch(void* const* d_in, const int* in_sizes, int n_in,
                              void* d_out, int out_size, void* d_ws, size_t ws_size,
                              hipStream_t stream) {
    const int* op_idx = (const int*)d_in[0];
    const int* a_in   = (const int*)d_in[1];
    const int* b_in_i = (const int*)d_in[2];
    const int* c_in   = (const int*)d_in[3];
    const float* op_embed = (const float*)d_in[4];
    const float* W_in  = (const float*)d_in[5];
    const float* b_in  = (const float*)d_in[6];
    const float* Wr    = (const float*)d_in[7];
    const float* W1    = (const float*)d_in[8];
    const float* W2    = (const float*)d_in[9];
    const float* Wh1   = (const float*)d_in[10];
    const float* bh1   = (const float*)d_in[11];
    const float* Wh2   = (const float*)d_in[12];
    const float* bh2   = (const float*)d_in[13];

    const long B = in_sizes[0];  // 262144
    float* result = (float*)d_out;
    float* d_idx  = (float*)d_out + B * 8;
    float* d_aux  = (float*)d_out + B * 9;

    unsigned char* ws = (unsigned char*)d_ws;
    unsigned short* xq    = (unsigned short*)(ws + 0);            // 64 MB
    unsigned short* W1qT  = (unsigned short*)(ws + 67108864);     // 2 MB
    unsigned short* W2qT  = (unsigned short*)(ws + 69206016);     // 2 MB
    unsigned short* W23qT = (unsigned short*)(ws + 71303168);     // 1 MB
    float* gate  = (float*)(ws + 72351744);                       // 1 MB
    int*   bucket= (int*)  (ws + 73400320);                       // 1 MB
    float* Ta    = (float*)(ws + 74448896);                       // 128 KB
    float* Tb    = (float*)(ws + 74579968);                       // 128 KB
    float* embW  = (float*)(ws + 74711040);                       // 4 KB
    float* Tc    = (float*)(ws + 74715136);                       // 512 B
    float* TaR   = (float*)(ws + 74715648);                       // 16 KB
    float* TbR   = (float*)(ws + 74732032);                       // 16 KB
    float* embWr = (float*)(ws + 74748416);                       // 512 B
    float* TcR   = (float*)(ws + 74748928);                       // 64 B
    float* partials = (float*)(ws + 74748992);                    // 2 KB
    unsigned char* acc = ws + 74751040;
    float* ternsum = (float*)(acc + 0);
    float* psum    = (float*)(acc + 64);
    int*   cnt     = (int*)(acc + 128);
    int*   fill    = (int*)(acc + 192);

    hipMemsetAsync(acc, 0, 256, stream);

    k_prep1<<<773, 256, 0, stream>>>(W1, W2, partials, op_embed, W_in, b_in,
                                     embW, Ta, Tb, Tc);
    k_prep2<<<545, 256, 0, stream>>>(W1, W2, partials, W1qT, W2qT, ternsum,
                                     embW, Ta, Tb, Tc, Wr, embWr, TaR, TbR, TcR);
    k_main3<<<2048, 256, 0, stream>>>(op_idx, a_in, b_in_i, c_in,
                                      embW, Ta, Tb, Tc, embWr, TaR, TbR, TcR,
                                      xq, gate, psum, cnt, d_idx,
                                      W2qT, Wh1, W23qT);
    k_scatter<<<(int)(B / 256), 256, 0, stream>>>(d_idx, cnt, fill, bucket);
    k_ffn<<<4112, 256, 36640, stream>>>(xq, gate, bucket, cnt, psum, ternsum,
                                        W1qT, W23qT, Wh2, bh1, bh2, result, d_aux);
}

// Round 5
// 264.418 us; speedup vs baseline: 1.1935x; 1.0082x over previous
//
#include <hip/hip_runtime.h>
#include <hip/hip_bf16.h>
#include <math.h>

typedef __attribute__((ext_vector_type(8))) short short8;
typedef __attribute__((ext_vector_type(4))) float floatx4;
typedef __attribute__((ext_vector_type(4))) unsigned int uintx4;

__device__ __forceinline__ unsigned short f2bf(float f) {
    unsigned int u = __float_as_uint(f);
    unsigned int r = (u + 0x7fffu + ((u >> 16) & 1u)) >> 16;
    return (unsigned short)r;
}

// single-instruction RNE pack: low16 <- a, high16 <- b
__device__ __forceinline__ unsigned int cvtpk(float a, float b) {
    unsigned int r;
    asm("v_cvt_pk_bf16_f32 %0, %1, %2" : "=v"(r) : "v"(a), "v"(b));
    return r;
}

// swap a's upper 32 lanes with b's lower 32 lanes
__device__ __forceinline__ void permlane32_swap(unsigned int &a, unsigned int &b) {
    asm volatile("v_permlane32_swap_b32 %0, %1" : "+v"(a), "+v"(b));
}
// swap a's odd 16-lane groups with b's even 16-lane groups
__device__ __forceinline__ void permlane16_swap(unsigned int &a, unsigned int &b) {
    asm volatile("v_permlane16_swap_b32 %0, %1" : "+v"(a), "+v"(b));
}

// gelu(u) = u * sigmoid(1.5957691216*u*(1+0.044715*u^2))
// log2e folded: z = -(k1 + k3*u^2)*u, e = 2^z
__device__ __forceinline__ float gelu_f(float u) {
    float u2 = u * u;
    float p = __builtin_fmaf(u2, -0.102943242f, -2.302208184f);
    float z = p * u;
    float e;
    asm("v_exp_f32 %0, %1" : "=v"(e) : "v"(z));
    return u * __builtin_amdgcn_rcpf(1.0f + e);
}

__device__ __forceinline__ floatx4 mfma16(short8 a, short8 b, floatx4 c) {
    return __builtin_amdgcn_mfma_f32_16x16x32_bf16(a, b, c, 0, 0, 0);
}

// ---------------- Stage 1: |W| partial sums  ∪  input tables ----------------
// blocks [0,512): sumabs; blocks [512,773): tables

__global__ __launch_bounds__(256) void k_prep1(
        const float* __restrict__ W1, const float* __restrict__ W2,
        float* __restrict__ partials,
        const float* __restrict__ op_embed, const float* __restrict__ W_in,
        const float* __restrict__ b_in,
        float* embW, float* Ta, float* Tb, float* Tc) {
    __shared__ float red[256];
    int bid = blockIdx.x;
    if (bid < 512) {
        bool isW1 = bid < 256;
        const float* W = (isW1 ? W1 : W2) + (long)(isW1 ? bid : bid - 256) * 4096;
        float s = 0.f;
        #pragma unroll
        for (int i = 0; i < 4; i++) {
            floatx4 v = *(const floatx4*)(W + i * 1024 + threadIdx.x * 4);
            s += fabsf(v[0]) + fabsf(v[1]) + fabsf(v[2]) + fabsf(v[3]);
        }
        red[threadIdx.x] = s; __syncthreads();
        for (int st = 128; st > 0; st >>= 1) {
            if (threadIdx.x < st) red[threadIdx.x] += red[threadIdx.x + st];
            __syncthreads();
        }
        if (threadIdx.x == 0) partials[bid] = red[0];
    } else {
        int i = (bid - 512) * 256 + threadIdx.x;
        if (i < 1024) {
            int op = i >> 7, j = i & 127;
            float s = b_in[j];
            #pragma unroll
            for (int k = 0; k < 32; k++) s += op_embed[op * 32 + k] * W_in[k * 128 + j];
            embW[i] = s;
        } else if (i < 1024 + 32768) {
            int r = i - 1024; int a = r >> 7, j = r & 127;
            float s = 0.f;
            #pragma unroll
            for (int bit = 0; bit < 8; bit++) if ((a >> bit) & 1) s += W_in[(32 + bit) * 128 + j];
            Ta[r] = s;
        } else if (i < 33792 + 32768) {
            int r = i - 33792; int b = r >> 7, j = r & 127;
            float s = 0.f;
            #pragma unroll
            for (int bit = 0; bit < 8; bit++) if ((b >> bit) & 1) s += W_in[(40 + bit) * 128 + j];
            Tb[r] = s;
        } else if (i < 66560 + 128) {
            int j = i - 66560; Tc[j] = W_in[48 * 128 + j];
        }
    }
}

// ---------------- Stage 2: quantize  ∪  router tables ----------------
// blocks [0,512): quant (coalesced-output via LDS transpose); [512,545): tablesR

__global__ __launch_bounds__(256) void k_prep2(
        const float* __restrict__ W1, const float* __restrict__ W2,
        const float* __restrict__ partials,
        unsigned short* __restrict__ W1qT, unsigned short* __restrict__ W2qT,
        float* ternsum,
        const float* __restrict__ embW, const float* __restrict__ Ta,
        const float* __restrict__ Tb, const float* __restrict__ Tc,
        const float* __restrict__ Wr,
        float* embWr, float* TaR, float* TbR, float* TcR) {
    __shared__ unsigned short Lq[4096];
    __shared__ float red[256];
    int blk = blockIdx.x;
    if (blk >= 512) {
        int i = (blk - 512) * 256 + threadIdx.x;
        int row = i >> 4, t = i & 15;
        const float* src; float* dst;
        if (row < 8)        { src = embW + row * 128;        dst = embWr + i; }
        else if (row < 264) { src = Ta + (row - 8) * 128;    dst = TaR + (row - 8) * 16 + t; }
        else if (row < 520) { src = Tb + (row - 264) * 128;  dst = TbR + (row - 264) * 16 + t; }
        else if (row == 520){ src = Tc;                      dst = TcR + t; }
        else return;
        float s = 0.f;
        for (int j = 0; j < 128; j++) s += src[j] * Wr[j * 16 + t];
        *dst = s;
        return;
    }
    bool isW1 = blk < 256;
    int rb = isW1 ? blk : blk - 256;
    int t = rb >> 4, slab = rb & 15;
    const float* part = partials + (isW1 ? 0 : 256) + t * 16;
    float ssum = 0.f;
    #pragma unroll
    for (int i = 0; i < 16; i++) ssum += part[i];
    float s = ssum * (1.0f / 65536.0f);
    float thr = 0.7f * s;
    unsigned int us = (unsigned int)f2bf(s);   // bf16(+s); bf16(-s) = us|0x8000
    int tid = threadIdx.x;
    float dsum = 0.f;
    if (isW1) {
        // output W1qT[t] is [512 f][128 d]; slab = 32 f-rows. input W1[t] = [128 d][512 f]
        int f0 = slab * 32;
        int d = tid >> 1, fh = (tid & 1) * 16;
        const float* src = W1 + (long)t * 65536 + d * 512 + f0 + fh;
        #pragma unroll
        for (int i = 0; i < 4; i++) {
            floatx4 w = *(const floatx4*)(src + i * 4);
            #pragma unroll
            for (int r = 0; r < 4; r++) {
                float wv = w[r];
                float aw = fabsf(wv);
                bool big = aw > thr;
                dsum += big ? fabsf(aw - s) : aw;
                unsigned int sign15 = (__float_as_uint(wv) >> 16) & 0x8000u;
                unsigned short q = big ? (unsigned short)(us | sign15) : (unsigned short)0;
                Lq[(fh + i * 4 + r) * 128 + d] = q;   // [32 f][128 d]
            }
        }
    } else {
        // output W2qT[t] is [128 d][512 f]; slab = 8 d-rows. input W2[t] = [512 f][128 d]
        int d0 = slab * 8;
        int f = tid * 2;
        const float* src = W2 + (long)t * 65536 + f * 128 + d0;
        #pragma unroll
        for (int rr = 0; rr < 2; rr++) {
            #pragma unroll
            for (int i = 0; i < 2; i++) {
                floatx4 w = *(const floatx4*)(src + rr * 128 + i * 4);
                #pragma unroll
                for (int r = 0; r < 4; r++) {
                    float wv = w[r];
                    float aw = fabsf(wv);
                    bool big = aw > thr;
                    dsum += big ? fabsf(aw - s) : aw;
                    unsigned int sign15 = (__float_as_uint(wv) >> 16) & 0x8000u;
                    unsigned short q = big ? (unsigned short)(us | sign15) : (unsigned short)0;
                    Lq[(i * 4 + r) * 512 + f + rr] = q;   // [8 d][512 f]
                }
            }
        }
    }
    __syncthreads();
    unsigned short* dst = (isW1 ? W1qT : W2qT) + (long)t * 65536 + slab * 4096;
    const uintx4* Ls = (const uintx4*)Lq;
    uintx4* D4 = (uintx4*)dst;
    D4[tid] = Ls[tid];
    D4[tid + 256] = Ls[tid + 256];
    red[tid] = dsum; __syncthreads();
    for (int st2 = 128; st2 > 0; st2 >>= 1) {
        if (tid < st2) red[tid] += red[tid + st2];
        __syncthreads();
    }
    if (tid == 0) atomicAdd(ternsum, red[0]);
}

// ---------------- Stage 3: router front  ∪  W23 precompute ----------------
// blocks [0,1024): router only (x is reconstructed inside k_ffn from tables);
// blocks [1024,2048): w23

__global__ __launch_bounds__(256) void k_main3(
        const int* __restrict__ op_idx, const int* __restrict__ a_in,
        const int* __restrict__ b_in_i, const int* __restrict__ c_in,
        const float* __restrict__ embWr, const float* __restrict__ TaR,
        const float* __restrict__ TbR, const float* __restrict__ TcR,
        float* __restrict__ gate_out,
        float* psum, int* cnt, float* __restrict__ d_idx,
        const unsigned short* __restrict__ W2qT, const float* __restrict__ Wh1,
        unsigned short* __restrict__ W23qT) {
    __shared__ float sp[4][16];
    __shared__ int sc[4][16];
    __shared__ float wcol[128];

    if (blockIdx.x >= 1024) {
        int b2 = blockIdx.x - 1024;
        int t = b2 >> 6, h = b2 & 63;
        if (threadIdx.x < 128) wcol[threadIdx.x] = Wh1[threadIdx.x * 64 + h];
        __syncthreads();
        int k2 = threadIdx.x * 2;
        const unsigned short* w2 = W2qT + (long)t * 65536 + k2;
        float a0 = 0.f, a1 = 0.f;
        #pragma unroll 8
        for (int d = 0; d < 128; d++) {
            unsigned int u = *(const unsigned int*)(w2 + d * 512);
            float w = wcol[d];
            a0 += w * __uint_as_float(u << 16);
            a1 += w * __uint_as_float(u & 0xffff0000u);
        }
        *(unsigned int*)(W23qT + ((long)(t * 64 + h)) * 512 + k2) = cvtpk(a0, a1);
        return;
    }

    int gid = blockIdx.x * 256 + threadIdx.x;
    int lane = threadIdx.x & 63;
    int j = lane & 15;
    int grpbase = lane & 48;
    float psum_acc = 0.f; int cnt_acc = 0;

    #pragma unroll 1
    for (int it = 0; it < 16; it++) {
        int tok = it * 16384 + (gid >> 4);
        int op = op_idx[tok], a = a_in[tok], b = b_in_i[tok], c = c_in[tok];
        float cf = (float)c;

        float lg = embWr[op * 16 + j] + TaR[a * 16 + j] + TbR[b * 16 + j] + cf * TcR[j];
        float m = lg;
        m = fmaxf(m, __shfl_xor(m, 8, 16));
        m = fmaxf(m, __shfl_xor(m, 4, 16));
        m = fmaxf(m, __shfl_xor(m, 2, 16));
        m = fmaxf(m, __shfl_xor(m, 1, 16));
        float p = __expf(lg - m);
        float s = p;
        s += __shfl_xor(s, 8, 16);
        s += __shfl_xor(s, 4, 16);
        s += __shfl_xor(s, 2, 16);
        s += __shfl_xor(s, 1, 16);
        float g = __builtin_amdgcn_rcpf(s);
        unsigned long long ball = __ballot(lg == m);
        int bi = __ffsll((unsigned long long)((ball >> grpbase) & 0xffffULL)) - 1;
        psum_acc += p * g;
        cnt_acc += (j == bi) ? 1 : 0;
        if (j == 0) { gate_out[tok] = g; d_idx[tok] = (float)bi; }
    }

    psum_acc += __shfl_xor(psum_acc, 16);
    psum_acc += __shfl_xor(psum_acc, 32);
    cnt_acc += __shfl_xor(cnt_acc, 16);
    cnt_acc += __shfl_xor(cnt_acc, 32);
    int wv = threadIdx.x >> 6;
    if (lane < 16) { sp[wv][j] = psum_acc; sc[wv][j] = cnt_acc; }
    __syncthreads();
    if (threadIdx.x < 16) {
        int jj = threadIdx.x;
        atomicAdd(&psum[jj], sp[0][jj] + sp[1][jj] + sp[2][jj] + sp[3][jj]);
        atomicAdd(&cnt[jj], sc[0][jj] + sc[1][jj] + sc[2][jj] + sc[3][jj]);
    }
}

// ---------------- scatter (local prefix from cnt) ----------------

__global__ void k_scatter(const float* __restrict__ d_idx, const int* __restrict__ cnt,
                          int* fill, int* __restrict__ bucket) {
    __shared__ int lc[16], lbase[16];
    if (threadIdx.x < 16) lc[threadIdx.x] = 0;
    __syncthreads();
    int offs[16];
    {
        int off = 0;
        #pragma unroll
        for (int tt = 0; tt < 16; tt++) { offs[tt] = off; off += cnt[tt]; }
    }
    int tok = blockIdx.x * 256 + threadIdx.x;
    int t = (int)d_idx[tok];
    int lpos = atomicAdd(&lc[t], 1);
    __syncthreads();
    if (threadIdx.x < 16) lbase[threadIdx.x] = atomicAdd(&fill[threadIdx.x], lc[threadIdx.x]);
    __syncthreads();
    bucket[offs[t] + lbase[t] + lpos] = tok;
}

// ---------------- Phase C: MoE FFN + fused head ----------------
// x reconstructed IN-KERNEL from L2-resident tables (identical f32 math +
// cvtpk rounding as the old k_front pack -> bit-identical Ax; no xq buffer).
// GEMM1 -> gelu -> in-register permute -> GEMM2 (k-split, rotated h-blocks)
// -> 16KB round-robin reduce -> H overlays Ax -> fused head.
// nc loop fully unrolled + all 12 fragment loads hoisted to iteration top so
// the scheduler can overlap next-iter loads with current compute.
// launch_bounds(256,3): (256,4) spills (R3). Combined VGPR+AGPR ~148/170.

__global__ __launch_bounds__(256, 3) void k_ffn(
    const int* __restrict__ op_idx, const int* __restrict__ a_in,
    const int* __restrict__ b_in_i, const int* __restrict__ c_in,
    const float* __restrict__ embW, const float* __restrict__ Ta,
    const float* __restrict__ Tb, const float* __restrict__ Tc,
    const float* __restrict__ gate,
    const int* __restrict__ bucket, const int* __restrict__ cnt_g,
    const float* __restrict__ psum_g, const float* __restrict__ ternsum_g,
    const unsigned short* __restrict__ W1qT, const unsigned short* __restrict__ W23qT,
    const float* __restrict__ Wh2, const float* __restrict__ bh1,
    const float* __restrict__ bh2,
    float* __restrict__ result, float* __restrict__ d_aux) {

    extern __shared__ __align__(16) unsigned char smem[];
    unsigned short* Ax = (unsigned short*)smem;            // [64][136] bf16 = 17408 B; H f32 [64][68] overlays
    float* Red = (float*)(smem + 17408);                   // 16384 B: 4 slots x [4 mt][64 lane][4]
    int*   toks = (int*)(smem + 33792);                    // 256 B
    float* gats = (float*)(smem + 34048);                  // 256 B
    float* Wh2l = (float*)(smem + 34304);                  // 2048 B
    float* bh2l = (float*)(smem + 36352);                  // 32 B
    float* bh1l = (float*)(smem + 36384);                  // 256 B
    int*   opsl = (int*)(smem + 36640);                    // 256 B
    int*   asl  = (int*)(smem + 36896);                    // 256 B
    int*   bsl  = (int*)(smem + 37152);                    // 256 B
    float* csl  = (float*)(smem + 37408);                  // 256 B (end 37664)

    int bid = blockIdx.x;
    // per-block uniform bid -> (tile, chunk) mapping from cnt
    int t = -1, ci = 0, nt = 0, base = 0;
    {
        int coff = 0, off = 0;
        #pragma unroll 1
        for (int tt = 0; tt < 16; tt++) {
            int c = cnt_g[tt];
            int ch = (c + 63) >> 6;
            if (t < 0 && bid < coff + ch) { t = tt; ci = bid - coff; nt = c; base = off + ci * 64; }
            coff += ch; off += c;
        }
    }
    if (t < 0) return;
    int nvalid = nt - ci * 64; if (nvalid > 64) nvalid = 64;

    int tid = threadIdx.x;
    if (tid < 64) {
        int tk = (tid < nvalid) ? bucket[base + tid] : -1;
        toks[tid] = tk;
        int tks = (tk >= 0) ? tk : 0;
        gats[tid] = (tk >= 0) ? gate[tk] : 0.0f;   // gm=0 masks garbage rows
        opsl[tid] = op_idx[tks];
        asl[tid]  = a_in[tks];
        bsl[tid]  = b_in_i[tks];
        csl[tid]  = (float)c_in[tks];
    }
    Wh2l[tid] = Wh2[tid];
    Wh2l[tid + 256] = Wh2[tid + 256];
    if (tid < 8) bh2l[tid] = bh2[tid];
    else if (tid < 72) bh1l[tid - 8] = bh1[tid - 8];
    __syncthreads();

    // stage x rows: reconstruct from tables (L2-resident), identical rounding
    #pragma unroll
    for (int it = 0; it < 4; it++) {
        int seg = it * 256 + tid; int r = seg >> 4, sg = seg & 15;
        int d0 = sg * 8;
        int op = opsl[r], a = asl[r], b = bsl[r];
        float cf = csl[r];
        const floatx4* Ev = (const floatx4*)(embW + op * 128 + d0);
        const floatx4* A4 = (const floatx4*)(Ta + a * 128 + d0);
        const floatx4* B4 = (const floatx4*)(Tb + b * 128 + d0);
        const floatx4* C4 = (const floatx4*)(Tc + d0);
        floatx4 v0 = Ev[0] + A4[0] + B4[0] + cf * C4[0];
        floatx4 v1 = Ev[1] + A4[1] + B4[1] + cf * C4[1];
        uintx4 o;
        o[0] = cvtpk(v0[0], v0[1]);
        o[1] = cvtpk(v0[2], v0[3]);
        o[2] = cvtpk(v1[0], v1[1]);
        o[3] = cvtpk(v1[2], v1[3]);
        *(uintx4*)(Ax + r * 136 + sg * 8) = o;
    }
    __syncthreads();

    int lane = tid & 63, dh = tid >> 6;
    int lane15 = lane & 15, lgrp = lane >> 4;

    floatx4 acc3[4][4];   // [i][mt]; i-th slot = h-block (dh+i)&3 (rotated order)
    #pragma unroll
    for (int i = 0; i < 4; i++)
        #pragma unroll
        for (int j = 0; j < 4; j++) acc3[i][j] = (floatx4){0.f, 0.f, 0.f, 0.f};

    const unsigned short* w1p  = W1qT + (long)t * 65536 + (dh * 32 + lane15) * 128 + lgrp * 8;
    const unsigned short* w23p = W23qT + (long)t * 32768 + lane15 * 512 + dh * 32 + lgrp * 8;
    int ho0 = dh * 8192;
    int ho1 = ((dh + 1) & 3) * 8192;
    int ho2 = ((dh + 2) & 3) * 8192;
    int ho3 = ((dh + 3) & 3) * 8192;

    #pragma unroll
    for (int nc = 0; nc < 4; nc++) {
        const unsigned short* w1c = w1p + nc * 16384;
        const unsigned short* w23c = w23p + nc * 128;

        // hoisted fragment loads (12 x 16B): issue together at iteration top
        short8 a00 = *(const short8*)(w1c + 0 * 32);
        short8 a01 = *(const short8*)(w1c + 1 * 32);
        short8 a02 = *(const short8*)(w1c + 2 * 32);
        short8 a03 = *(const short8*)(w1c + 3 * 32);
        short8 a10 = *(const short8*)(w1c + 2048 + 0 * 32);
        short8 a11 = *(const short8*)(w1c + 2048 + 1 * 32);
        short8 a12 = *(const short8*)(w1c + 2048 + 2 * 32);
        short8 a13 = *(const short8*)(w1c + 2048 + 3 * 32);
        short8 af23_0 = *(const short8*)(w23c + ho0);
        short8 af23_1 = *(const short8*)(w23c + ho1);
        short8 af23_2 = *(const short8*)(w23c + ho2);
        short8 af23_3 = *(const short8*)(w23c + ho3);

        // GEMM1: A = W1 rows, B = Ax (LDS)
        floatx4 acc1[2][4];
        #pragma unroll
        for (int i = 0; i < 2; i++)
            #pragma unroll
            for (int j = 0; j < 4; j++) acc1[i][j] = (floatx4){0.f, 0.f, 0.f, 0.f};

        #pragma unroll
        for (int mt = 0; mt < 4; mt++) {
            int mrow = (mt * 16 + lane15) * 136;
            short8 bf0 = *(const short8*)(Ax + mrow + 0 * 32 + lgrp * 8);
            short8 bf1 = *(const short8*)(Ax + mrow + 1 * 32 + lgrp * 8);
            short8 bf2 = *(const short8*)(Ax + mrow + 2 * 32 + lgrp * 8);
            short8 bf3 = *(const short8*)(Ax + mrow + 3 * 32 + lgrp * 8);
            acc1[0][mt] = mfma16(a00, bf0, acc1[0][mt]);
            acc1[1][mt] = mfma16(a10, bf0, acc1[1][mt]);
            acc1[0][mt] = mfma16(a01, bf1, acc1[0][mt]);
            acc1[1][mt] = mfma16(a11, bf1, acc1[1][mt]);
            acc1[0][mt] = mfma16(a02, bf2, acc1[0][mt]);
            acc1[1][mt] = mfma16(a12, bf2, acc1[1][mt]);
            acc1[0][mt] = mfma16(a03, bf3, acc1[0][mt]);
            acc1[1][mt] = mfma16(a13, bf3, acc1[1][mt]);
        }

        // fuse: gelu -> cvtpk -> lane permute -> B-fragment -> 4 MFMAs (per mt)
        #pragma unroll
        for (int mt = 0; mt < 4; mt++) {
            floatx4 v0 = acc1[0][mt], v1 = acc1[1][mt];
            unsigned int X0 = cvtpk(gelu_f(v0[0]), gelu_f(v0[1]));
            unsigned int X1 = cvtpk(gelu_f(v0[2]), gelu_f(v0[3]));
            unsigned int Y0 = cvtpk(gelu_f(v1[0]), gelu_f(v1[1]));
            unsigned int Y1 = cvtpk(gelu_f(v1[2]), gelu_f(v1[3]));
            permlane32_swap(X0, Y0);
            permlane16_swap(X0, Y0);
            permlane32_swap(X1, Y1);
            permlane16_swap(X1, Y1);
            union { uintx4 u; short8 s; } bu;
            bu.u[0] = X0; bu.u[1] = X1; bu.u[2] = Y0; bu.u[3] = Y1;
            short8 bfrag = bu.s;
            acc3[0][mt] = mfma16(af23_0, bfrag, acc3[0][mt]);
            acc3[1][mt] = mfma16(af23_1, bfrag, acc3[1][mt]);
            acc3[2][mt] = mfma16(af23_2, bfrag, acc3[2][mt]);
            acc3[3][mt] = mfma16(af23_3, bfrag, acc3[3][mt]);
        }
    }

    // ---- cross-wave k-reduction: 3-round round-robin via one 16KB buffer ----
    floatx4 fin[4];
    #pragma unroll
    for (int mt = 0; mt < 4; mt++) fin[mt] = acc3[0][mt];
    float* myslot = Red + dh * 1024;
    int lofs = lane * 4;
    // round 1
    #pragma unroll
    for (int mt = 0; mt < 4; mt++)
        *(floatx4*)(myslot + mt * 256 + lofs) = acc3[1][mt];
    __syncthreads();
    {
        const float* ps = Red + ((dh + 3) & 3) * 1024;
        #pragma unroll
        for (int mt = 0; mt < 4; mt++)
            fin[mt] += *(const floatx4*)(ps + mt * 256 + lofs);
    }
    __syncthreads();
    // round 2
    #pragma unroll
    for (int mt = 0; mt < 4; mt++)
        *(floatx4*)(myslot + mt * 256 + lofs) = acc3[2][mt];
    __syncthreads();
    {
        const float* ps = Red + ((dh + 2) & 3) * 1024;
        #pragma unroll
        for (int mt = 0; mt < 4; mt++)
            fin[mt] += *(const floatx4*)(ps + mt * 256 + lofs);
    }
    __syncthreads();
    // round 3
    #pragma unroll
    for (int mt = 0; mt < 4; mt++)
        *(floatx4*)(myslot + mt * 256 + lofs) = acc3[3][mt];
    __syncthreads();
    {
        const float* ps = Red + ((dh + 1) & 3) * 1024;
        #pragma unroll
        for (int mt = 0; mt < 4; mt++)
            fin[mt] += *(const floatx4*)(ps + mt * 256 + lofs);
    }

    // H overlays Ax (dead after nc loop; ordered by the reduce barriers)
    float* H = (float*)Ax;                   // [64 m][68] f32 = 17408 B
    int hb = dh * 16 + lgrp * 4;
    floatx4 b4 = *(const floatx4*)(bh1l + hb);
    #pragma unroll
    for (int mt = 0; mt < 4; mt++) {
        int m = mt * 16 + lane15;
        float gm = gats[m];
        floatx4 v;
        v[0] = fmaxf(fin[mt][0] * gm + b4[0], 0.f);
        v[1] = fmaxf(fin[mt][1] * gm + b4[1], 0.f);
        v[2] = fmaxf(fin[mt][2] * gm + b4[2], 0.f);
        v[3] = fmaxf(fin[mt][3] * gm + b4[3], 0.f);
        *(floatx4*)(H + m * 68 + hb) = v;
    }
    __syncthreads();                         // H complete

    int mloc = tid >> 2, c0 = (tid & 3) * 2;
    int tk = toks[mloc];
    float z0 = bh2l[c0], z1 = bh2l[c0 + 1];
    const floatx4* Hr4 = (const floatx4*)(H + mloc * 68);
    #pragma unroll
    for (int h4 = 0; h4 < 16; h4++) {
        floatx4 hv = Hr4[h4];
        #pragma unroll
        for (int r = 0; r < 4; r++) {
            int h = h4 * 4 + r;
            z0 += hv[r] * Wh2l[h * 8 + c0];
            z1 += hv[r] * Wh2l[h * 8 + c0 + 1];
        }
    }
    if (tk >= 0) {
        float2 rr;
        rr.x = __builtin_amdgcn_rcpf(1.0f + __expf(-z0));
        rr.y = __builtin_amdgcn_rcpf(1.0f + __expf(-z1));
        *(float2*)(result + (long)tk * 8 + c0) = rr;
    }

    // aux loss (block 0 only)
    if (bid == 0 && tid == 0) {
        const float Bf = 262144.0f;
        float tern = ternsum_g[0] * (1.0f / 1048576.0f);
        float sp = 0.f; float cp[4] = {0.f, 0.f, 0.f, 0.f};
        for (int tt = 0; tt < 16; tt++) {
            float frac = (float)cnt_g[tt] / Bf, mp = psum_g[tt] / Bf;
            sp += frac * mp; cp[tt >> 2] += mp;
        }
        float dv = 0.f;
        for (int cc = 0; cc < 4; cc++) dv += cp[cc] * logf(cp[cc] + 1e-9f);
        d_aux[0] = 0.01f * tern + 0.005f * (16.0f * sp) + 0.01f * dv;
    }
}

// ---------------- launch ----------------

extern "C" void kernel_launch(void* const* d_in, const int* in_sizes, int n_in,
                              void* d_out, int out_size, void* d_ws, size_t ws_size,
                              hipStream_t stream) {
    const int* op_idx = (const int*)d_in[0];
    const int* a_in   = (const int*)d_in[1];
    const int* b_in_i = (const int*)d_in[2];
    const int* c_in   = (const int*)d_in[3];
    const float* op_embed = (const float*)d_in[4];
    const float* W_in  = (const float*)d_in[5];
    const float* b_in  = (const float*)d_in[6];
    const float* Wr    = (const float*)d_in[7];
    const float* W1    = (const float*)d_in[8];
    const float* W2    = (const float*)d_in[9];
    const float* Wh1   = (const float*)d_in[10];
    const float* bh1   = (const float*)d_in[11];
    const float* Wh2   = (const float*)d_in[12];
    const float* bh2   = (const float*)d_in[13];

    const long B = in_sizes[0];  // 262144
    float* result = (float*)d_out;
    float* d_idx  = (float*)d_out + B * 8;
    float* d_aux  = (float*)d_out + B * 9;

    unsigned char* ws = (unsigned char*)d_ws;
    unsigned short* W1qT  = (unsigned short*)(ws + 67108864);     // 2 MB
    unsigned short* W2qT  = (unsigned short*)(ws + 69206016);     // 2 MB
    unsigned short* W23qT = (unsigned short*)(ws + 71303168);     // 1 MB
    float* gate  = (float*)(ws + 72351744);                       // 1 MB
    int*   bucket= (int*)  (ws + 73400320);                       // 1 MB
    float* Ta    = (float*)(ws + 74448896);                       // 128 KB
    float* Tb    = (float*)(ws + 74579968);                       // 128 KB
    float* embW  = (float*)(ws + 74711040);                       // 4 KB
    float* Tc    = (float*)(ws + 74715136);                       // 512 B
    float* TaR   = (float*)(ws + 74715648);                       // 16 KB
    float* TbR   = (float*)(ws + 74732032);                       // 16 KB
    float* embWr = (float*)(ws + 74748416);                       // 512 B
    float* TcR   = (float*)(ws + 74748928);                       // 64 B
    float* partials = (float*)(ws + 74748992);                    // 2 KB
    unsigned char* acc = ws + 74751040;
    float* ternsum = (float*)(acc + 0);
    float* psum    = (float*)(acc + 64);
    int*   cnt     = (int*)(acc + 128);
    int*   fill    = (int*)(acc + 192);

    hipMemsetAsync(acc, 0, 256, stream);

    k_prep1<<<773, 256, 0, stream>>>(W1, W2, partials, op_embed, W_in, b_in,
                                     embW, Ta, Tb, Tc);
    k_prep2<<<545, 256, 0, stream>>>(W1, W2, partials, W1qT, W2qT, ternsum,
                                     embW, Ta, Tb, Tc, Wr, embWr, TaR, TbR, TcR);
    k_main3<<<2048, 256, 0, stream>>>(op_idx, a_in, b_in_i, c_in,
                                      embWr, TaR, TbR, TcR,
                                      gate, psum, cnt, d_idx,
                                      W2qT, Wh1, W23qT);
    k_scatter<<<(int)(B / 256), 256, 0, stream>>>(d_idx, cnt, fill, bucket);
    k_ffn<<<4112, 256, 37664, stream>>>(op_idx, a_in, b_in_i, c_in,
                                        embW, Ta, Tb, Tc,
                                        gate, bucket, cnt, psum, ternsum,
                                        W1qT, W23qT, Wh2, bh1, bh2, result, d_aux);
}

// Round 6
// 252.560 us; speedup vs baseline: 1.2495x; 1.0470x over previous
//
#include <hip/hip_runtime.h>
#include <hip/hip_bf16.h>
#include <math.h>

typedef __attribute__((ext_vector_type(8))) short short8;
typedef __attribute__((ext_vector_type(4))) float floatx4;
typedef __attribute__((ext_vector_type(4))) unsigned int uintx4;

#define BUCKET_CAP 262144

__device__ __forceinline__ unsigned short f2bf(float f) {
    unsigned int u = __float_as_uint(f);
    unsigned int r = (u + 0x7fffu + ((u >> 16) & 1u)) >> 16;
    return (unsigned short)r;
}

// single-instruction RNE pack: low16 <- a, high16 <- b
__device__ __forceinline__ unsigned int cvtpk(float a, float b) {
    unsigned int r;
    asm("v_cvt_pk_bf16_f32 %0, %1, %2" : "=v"(r) : "v"(a), "v"(b));
    return r;
}

// swap a's upper 32 lanes with b's lower 32 lanes
__device__ __forceinline__ void permlane32_swap(unsigned int &a, unsigned int &b) {
    asm volatile("v_permlane32_swap_b32 %0, %1" : "+v"(a), "+v"(b));
}
// swap a's odd 16-lane groups with b's even 16-lane groups
__device__ __forceinline__ void permlane16_swap(unsigned int &a, unsigned int &b) {
    asm volatile("v_permlane16_swap_b32 %0, %1" : "+v"(a), "+v"(b));
}

// gelu(u) = u * sigmoid(1.5957691216*u*(1+0.044715*u^2))
// log2e folded: z = -(k1 + k3*u^2)*u, e = 2^z
__device__ __forceinline__ float gelu_f(float u) {
    float u2 = u * u;
    float p = __builtin_fmaf(u2, -0.102943242f, -2.302208184f);
    float z = p * u;
    float e;
    asm("v_exp_f32 %0, %1" : "=v"(e) : "v"(z));
    return u * __builtin_amdgcn_rcpf(1.0f + e);
}

__device__ __forceinline__ floatx4 mfma16(short8 a, short8 b, floatx4 c) {
    return __builtin_amdgcn_mfma_f32_16x16x32_bf16(a, b, c, 0, 0, 0);
}

// ---------------- Stage 1: |W| partial sums  ∪  input tables ----------------
// blocks [0,512): sumabs; blocks [512,773): tables

__global__ __launch_bounds__(256) void k_prep1(
        const float* __restrict__ W1, const float* __restrict__ W2,
        float* __restrict__ partials,
        const float* __restrict__ op_embed, const float* __restrict__ W_in,
        const float* __restrict__ b_in,
        float* embW, float* Ta, float* Tb, float* Tc) {
    __shared__ float red[256];
    int bid = blockIdx.x;
    if (bid < 512) {
        bool isW1 = bid < 256;
        const float* W = (isW1 ? W1 : W2) + (long)(isW1 ? bid : bid - 256) * 4096;
        float s = 0.f;
        #pragma unroll
        for (int i = 0; i < 4; i++) {
            floatx4 v = *(const floatx4*)(W + i * 1024 + threadIdx.x * 4);
            s += fabsf(v[0]) + fabsf(v[1]) + fabsf(v[2]) + fabsf(v[3]);
        }
        red[threadIdx.x] = s; __syncthreads();
        for (int st = 128; st > 0; st >>= 1) {
            if (threadIdx.x < st) red[threadIdx.x] += red[threadIdx.x + st];
            __syncthreads();
        }
        if (threadIdx.x == 0) partials[bid] = red[0];
    } else {
        int i = (bid - 512) * 256 + threadIdx.x;
        if (i < 1024) {
            int op = i >> 7, j = i & 127;
            float s = b_in[j];
            #pragma unroll
            for (int k = 0; k < 32; k++) s += op_embed[op * 32 + k] * W_in[k * 128 + j];
            embW[i] = s;
        } else if (i < 1024 + 32768) {
            int r = i - 1024; int a = r >> 7, j = r & 127;
            float s = 0.f;
            #pragma unroll
            for (int bit = 0; bit < 8; bit++) if ((a >> bit) & 1) s += W_in[(32 + bit) * 128 + j];
            Ta[r] = s;
        } else if (i < 33792 + 32768) {
            int r = i - 33792; int b = r >> 7, j = r & 127;
            float s = 0.f;
            #pragma unroll
            for (int bit = 0; bit < 8; bit++) if ((b >> bit) & 1) s += W_in[(40 + bit) * 128 + j];
            Tb[r] = s;
        } else if (i < 66560 + 128) {
            int j = i - 66560; Tc[j] = W_in[48 * 128 + j];
        }
    }
}

// ---------------- Stage 2: quantize  ∪  router tables ----------------
// blocks [0,512): quant (coalesced-output via LDS transpose); [512,545): tablesR

__global__ __launch_bounds__(256) void k_prep2(
        const float* __restrict__ W1, const float* __restrict__ W2,
        const float* __restrict__ partials,
        unsigned short* __restrict__ W1qT, unsigned short* __restrict__ W2qT,
        float* ternsum,
        const float* __restrict__ embW, const float* __restrict__ Ta,
        const float* __restrict__ Tb, const float* __restrict__ Tc,
        const float* __restrict__ Wr,
        float* embWr, float* TaR, float* TbR, float* TcR) {
    __shared__ unsigned short Lq[4096];
    __shared__ float red[256];
    int blk = blockIdx.x;
    if (blk >= 512) {
        int i = (blk - 512) * 256 + threadIdx.x;
        int row = i >> 4, t = i & 15;
        const float* src; float* dst;
        if (row < 8)        { src = embW + row * 128;        dst = embWr + i; }
        else if (row < 264) { src = Ta + (row - 8) * 128;    dst = TaR + (row - 8) * 16 + t; }
        else if (row < 520) { src = Tb + (row - 264) * 128;  dst = TbR + (row - 264) * 16 + t; }
        else if (row == 520){ src = Tc;                      dst = TcR + t; }
        else return;
        float s = 0.f;
        for (int j = 0; j < 128; j++) s += src[j] * Wr[j * 16 + t];
        *dst = s;
        return;
    }
    bool isW1 = blk < 256;
    int rb = isW1 ? blk : blk - 256;
    int t = rb >> 4, slab = rb & 15;
    const float* part = partials + (isW1 ? 0 : 256) + t * 16;
    float ssum = 0.f;
    #pragma unroll
    for (int i = 0; i < 16; i++) ssum += part[i];
    float s = ssum * (1.0f / 65536.0f);
    float thr = 0.7f * s;
    unsigned int us = (unsigned int)f2bf(s);   // bf16(+s); bf16(-s) = us|0x8000
    int tid = threadIdx.x;
    float dsum = 0.f;
    if (isW1) {
        // output W1qT[t] is [512 f][128 d]; slab = 32 f-rows. input W1[t] = [128 d][512 f]
        int f0 = slab * 32;
        int d = tid >> 1, fh = (tid & 1) * 16;
        const float* src = W1 + (long)t * 65536 + d * 512 + f0 + fh;
        #pragma unroll
        for (int i = 0; i < 4; i++) {
            floatx4 w = *(const floatx4*)(src + i * 4);
            #pragma unroll
            for (int r = 0; r < 4; r++) {
                float wv = w[r];
                float aw = fabsf(wv);
                bool big = aw > thr;
                dsum += big ? fabsf(aw - s) : aw;
                unsigned int sign15 = (__float_as_uint(wv) >> 16) & 0x8000u;
                unsigned short q = big ? (unsigned short)(us | sign15) : (unsigned short)0;
                Lq[(fh + i * 4 + r) * 128 + d] = q;   // [32 f][128 d]
            }
        }
    } else {
        // output W2qT[t] is [128 d][512 f]; slab = 8 d-rows. input W2[t] = [512 f][128 d]
        int d0 = slab * 8;
        int f = tid * 2;
        const float* src = W2 + (long)t * 65536 + f * 128 + d0;
        #pragma unroll
        for (int rr = 0; rr < 2; rr++) {
            #pragma unroll
            for (int i = 0; i < 2; i++) {
                floatx4 w = *(const floatx4*)(src + rr * 128 + i * 4);
                #pragma unroll
                for (int r = 0; r < 4; r++) {
                    float wv = w[r];
                    float aw = fabsf(wv);
                    bool big = aw > thr;
                    dsum += big ? fabsf(aw - s) : aw;
                    unsigned int sign15 = (__float_as_uint(wv) >> 16) & 0x8000u;
                    unsigned short q = big ? (unsigned short)(us | sign15) : (unsigned short)0;
                    Lq[(i * 4 + r) * 512 + f + rr] = q;   // [8 d][512 f]
                }
            }
        }
    }
    __syncthreads();
    unsigned short* dst = (isW1 ? W1qT : W2qT) + (long)t * 65536 + slab * 4096;
    const uintx4* Ls = (const uintx4*)Lq;
    uintx4* D4 = (uintx4*)dst;
    D4[tid] = Ls[tid];
    D4[tid + 256] = Ls[tid + 256];
    red[tid] = dsum; __syncthreads();
    for (int st2 = 128; st2 > 0; st2 >>= 1) {
        if (tid < st2) red[tid] += red[tid + st2];
        __syncthreads();
    }
    if (tid == 0) atomicAdd(ternsum, red[0]);
}

// ---------------- Stage 3: router front + fused scatter  ∪  W23 ----------------
// blocks [0,1024): router + bucket-scatter (fixed-capacity buckets: slot base
// t*BUCKET_CAP, so no global prefix over cnt is needed);
// blocks [1024,2048): w23

__global__ __launch_bounds__(256) void k_main3(
        const int* __restrict__ op_idx, const int* __restrict__ a_in,
        const int* __restrict__ b_in_i, const int* __restrict__ c_in,
        const float* __restrict__ embWr, const float* __restrict__ TaR,
        const float* __restrict__ TbR, const float* __restrict__ TcR,
        float* __restrict__ gate_out,
        float* psum, int* cnt, int* fill, int* __restrict__ bucket,
        float* __restrict__ d_idx,
        const unsigned short* __restrict__ W2qT, const float* __restrict__ Wh1,
        unsigned short* __restrict__ W23qT) {
    __shared__ float sp[4][16];
    __shared__ int sc[4][16];
    __shared__ float wcol[128];
    __shared__ int lc[16], lbase[16];
    __shared__ unsigned char blE[256];   // bucket id per local token entry
    __shared__ unsigned char lpE[256];   // local pos per entry (<=255)

    if (blockIdx.x >= 1024) {
        int b2 = blockIdx.x - 1024;
        int t = b2 >> 6, h = b2 & 63;
        if (threadIdx.x < 128) wcol[threadIdx.x] = Wh1[threadIdx.x * 64 + h];
        __syncthreads();
        int k2 = threadIdx.x * 2;
        const unsigned short* w2 = W2qT + (long)t * 65536 + k2;
        float a0 = 0.f, a1 = 0.f;
        #pragma unroll 8
        for (int d = 0; d < 128; d++) {
            unsigned int u = *(const unsigned int*)(w2 + d * 512);
            float w = wcol[d];
            a0 += w * __uint_as_float(u << 16);
            a1 += w * __uint_as_float(u & 0xffff0000u);
        }
        *(unsigned int*)(W23qT + ((long)(t * 64 + h)) * 512 + k2) = cvtpk(a0, a1);
        return;
    }

    int tid = threadIdx.x;
    if (tid < 16) lc[tid] = 0;
    __syncthreads();

    int gid = blockIdx.x * 256 + tid;
    int lane = tid & 63;
    int j = lane & 15;
    int grpbase = lane & 48;
    int tl = tid >> 4;                   // local token-group index (0..15)
    float psum_acc = 0.f; int cnt_acc = 0;

    #pragma unroll 1
    for (int it = 0; it < 16; it++) {
        int tok = it * 16384 + (gid >> 4);
        int op = op_idx[tok], a = a_in[tok], b = b_in_i[tok], c = c_in[tok];
        float cf = (float)c;

        float lg = embWr[op * 16 + j] + TaR[a * 16 + j] + TbR[b * 16 + j] + cf * TcR[j];
        float m = lg;
        m = fmaxf(m, __shfl_xor(m, 8, 16));
        m = fmaxf(m, __shfl_xor(m, 4, 16));
        m = fmaxf(m, __shfl_xor(m, 2, 16));
        m = fmaxf(m, __shfl_xor(m, 1, 16));
        float p = __expf(lg - m);
        float s = p;
        s += __shfl_xor(s, 8, 16);
        s += __shfl_xor(s, 4, 16);
        s += __shfl_xor(s, 2, 16);
        s += __shfl_xor(s, 1, 16);
        float g = __builtin_amdgcn_rcpf(s);
        unsigned long long ball = __ballot(lg == m);
        int bi = __ffsll((unsigned long long)((ball >> grpbase) & 0xffffULL)) - 1;
        psum_acc += p * g;
        cnt_acc += (j == bi) ? 1 : 0;
        if (j == bi) {
            int lpos = atomicAdd(&lc[bi], 1);
            int e = it * 16 + tl;
            blE[e] = (unsigned char)bi;
            lpE[e] = (unsigned char)lpos;
        }
        if (j == 0) { gate_out[tok] = g; d_idx[tok] = (float)bi; }
    }

    psum_acc += __shfl_xor(psum_acc, 16);
    psum_acc += __shfl_xor(psum_acc, 32);
    cnt_acc += __shfl_xor(cnt_acc, 16);
    cnt_acc += __shfl_xor(cnt_acc, 32);
    int wv = tid >> 6;
    if (lane < 16) { sp[wv][j] = psum_acc; sc[wv][j] = cnt_acc; }
    __syncthreads();
    if (tid < 16) {
        atomicAdd(&psum[tid], sp[0][tid] + sp[1][tid] + sp[2][tid] + sp[3][tid]);
        atomicAdd(&cnt[tid], sc[0][tid] + sc[1][tid] + sc[2][tid] + sc[3][tid]);
        lbase[tid] = atomicAdd(&fill[tid], lc[tid]);
    }
    __syncthreads();
    // finalize: each thread writes one token's bucket slot
    {
        int e = tid;
        int bi = (int)blE[e];
        int tok = (e >> 4) * 16384 + blockIdx.x * 16 + (e & 15);
        bucket[bi * BUCKET_CAP + lbase[bi] + (int)lpE[e]] = tok;
    }
}

// ---------------- Phase C: MoE FFN + fused head ----------------
// x reconstructed IN-KERNEL from L2-resident tables (identical f32 math +
// cvtpk rounding -> bit-identical Ax; no xq buffer).
// GEMM1 -> gelu -> in-register permute -> GEMM2 (k-split, rotated h-blocks)
// -> 16KB round-robin reduce -> H overlays Ax -> fused head.
// Inner loop: R4's NON-hoisted form (loads adjacent to consumers) — the R5
// hoist/unroll regressed 127->135 us; compiler schedules this form better.
// launch_bounds(256,3): (256,4) spills (R3). Combined VGPR+AGPR ~148/170.

__global__ __launch_bounds__(256, 3) void k_ffn(
    const int* __restrict__ op_idx, const int* __restrict__ a_in,
    const int* __restrict__ b_in_i, const int* __restrict__ c_in,
    const float* __restrict__ embW, const float* __restrict__ Ta,
    const float* __restrict__ Tb, const float* __restrict__ Tc,
    const float* __restrict__ gate,
    const int* __restrict__ bucket, const int* __restrict__ cnt_g,
    const float* __restrict__ psum_g, const float* __restrict__ ternsum_g,
    const unsigned short* __restrict__ W1qT, const unsigned short* __restrict__ W23qT,
    const float* __restrict__ Wh2, const float* __restrict__ bh1,
    const float* __restrict__ bh2,
    float* __restrict__ result, float* __restrict__ d_aux) {

    extern __shared__ __align__(16) unsigned char smem[];
    unsigned short* Ax = (unsigned short*)smem;            // [64][136] bf16 = 17408 B; H f32 [64][68] overlays
    float* Red = (float*)(smem + 17408);                   // 16384 B: 4 slots x [4 mt][64 lane][4]
    int*   toks = (int*)(smem + 33792);                    // 256 B
    float* gats = (float*)(smem + 34048);                  // 256 B
    float* Wh2l = (float*)(smem + 34304);                  // 2048 B
    float* bh2l = (float*)(smem + 36352);                  // 32 B
    float* bh1l = (float*)(smem + 36384);                  // 256 B
    int*   opsl = (int*)(smem + 36640);                    // 256 B
    int*   asl  = (int*)(smem + 36896);                    // 256 B
    int*   bsl  = (int*)(smem + 37152);                    // 256 B
    float* csl  = (float*)(smem + 37408);                  // 256 B (end 37664)

    int bid = blockIdx.x;
    // per-block uniform bid -> (tile, chunk) mapping from cnt
    int t = -1, ci = 0, nt = 0, base = 0;
    {
        int coff = 0;
        #pragma unroll 1
        for (int tt = 0; tt < 16; tt++) {
            int c = cnt_g[tt];
            int ch = (c + 63) >> 6;
            if (t < 0 && bid < coff + ch) {
                t = tt; ci = bid - coff; nt = c;
                base = tt * BUCKET_CAP + ci * 64;
            }
            coff += ch;
        }
    }
    if (t < 0) return;
    int nvalid = nt - ci * 64; if (nvalid > 64) nvalid = 64;

    int tid = threadIdx.x;
    if (tid < 64) {
        int tk = (tid < nvalid) ? bucket[base + tid] : -1;
        toks[tid] = tk;
        int tks = (tk >= 0) ? tk : 0;
        gats[tid] = (tk >= 0) ? gate[tk] : 0.0f;   // gm=0 masks garbage rows
        opsl[tid] = op_idx[tks];
        asl[tid]  = a_in[tks];
        bsl[tid]  = b_in_i[tks];
        csl[tid]  = (float)c_in[tks];
    }
    Wh2l[tid] = Wh2[tid];
    Wh2l[tid + 256] = Wh2[tid + 256];
    if (tid < 8) bh2l[tid] = bh2[tid];
    else if (tid < 72) bh1l[tid - 8] = bh1[tid - 8];
    __syncthreads();

    // stage x rows: reconstruct from tables (L2-resident), identical rounding
    #pragma unroll
    for (int it = 0; it < 4; it++) {
        int seg = it * 256 + tid; int r = seg >> 4, sg = seg & 15;
        int d0 = sg * 8;
        int op = opsl[r], a = asl[r], b = bsl[r];
        float cf = csl[r];
        const floatx4* Ev = (const floatx4*)(embW + op * 128 + d0);
        const floatx4* A4 = (const floatx4*)(Ta + a * 128 + d0);
        const floatx4* B4 = (const floatx4*)(Tb + b * 128 + d0);
        const floatx4* C4 = (const floatx4*)(Tc + d0);
        floatx4 v0 = Ev[0] + A4[0] + B4[0] + cf * C4[0];
        floatx4 v1 = Ev[1] + A4[1] + B4[1] + cf * C4[1];
        uintx4 o;
        o[0] = cvtpk(v0[0], v0[1]);
        o[1] = cvtpk(v0[2], v0[3]);
        o[2] = cvtpk(v1[0], v1[1]);
        o[3] = cvtpk(v1[2], v1[3]);
        *(uintx4*)(Ax + r * 136 + sg * 8) = o;
    }
    __syncthreads();

    int lane = tid & 63, dh = tid >> 6;
    int lane15 = lane & 15, lgrp = lane >> 4;

    floatx4 acc3[4][4];   // [i][mt]; i-th slot = h-block (dh+i)&3 (rotated order)
    #pragma unroll
    for (int i = 0; i < 4; i++)
        #pragma unroll
        for (int j = 0; j < 4; j++) acc3[i][j] = (floatx4){0.f, 0.f, 0.f, 0.f};

    const unsigned short* w1p  = W1qT + (long)t * 65536 + (dh * 32 + lane15) * 128 + lgrp * 8;
    const unsigned short* w23p = W23qT + (long)t * 32768 + lane15 * 512 + dh * 32 + lgrp * 8;
    int ho0 = dh * 8192;
    int ho1 = ((dh + 1) & 3) * 8192;
    int ho2 = ((dh + 2) & 3) * 8192;
    int ho3 = ((dh + 3) & 3) * 8192;

    for (int nc = 0; nc < 4; nc++) {
        // GEMM1: A = W1 rows (global), B = Ax (LDS)
        floatx4 acc1[2][4];
        #pragma unroll
        for (int i = 0; i < 2; i++)
            #pragma unroll
            for (int j = 0; j < 4; j++) acc1[i][j] = (floatx4){0.f, 0.f, 0.f, 0.f};

        const unsigned short* w1c = w1p + nc * 16384;
        #pragma unroll
        for (int kk = 0; kk < 4; kk++) {
            short8 af0 = *(const short8*)(w1c + kk * 32);
            short8 af1 = *(const short8*)(w1c + 2048 + kk * 32);
            int ko = kk * 32 + lgrp * 8;
            #pragma unroll
            for (int mt = 0; mt < 4; mt++) {
                short8 bf = *(const short8*)(Ax + (mt * 16 + lane15) * 136 + ko);
                acc1[0][mt] = mfma16(af0, bf, acc1[0][mt]);
                acc1[1][mt] = mfma16(af1, bf, acc1[1][mt]);
            }
        }

        // A-fragments for GEMM2, rotated h-block order
        const unsigned short* w23c = w23p + nc * 128;
        short8 af23_0 = *(const short8*)(w23c + ho0);
        short8 af23_1 = *(const short8*)(w23c + ho1);
        short8 af23_2 = *(const short8*)(w23c + ho2);
        short8 af23_3 = *(const short8*)(w23c + ho3);

        // fuse: gelu -> cvtpk -> lane permute -> B-fragment -> 4 MFMAs (per mt)
        #pragma unroll
        for (int mt = 0; mt < 4; mt++) {
            floatx4 v0 = acc1[0][mt], v1 = acc1[1][mt];
            unsigned int X0 = cvtpk(gelu_f(v0[0]), gelu_f(v0[1]));
            unsigned int X1 = cvtpk(gelu_f(v0[2]), gelu_f(v0[3]));
            unsigned int Y0 = cvtpk(gelu_f(v1[0]), gelu_f(v1[1]));
            unsigned int Y1 = cvtpk(gelu_f(v1[2]), gelu_f(v1[3]));
            permlane32_swap(X0, Y0);
            permlane16_swap(X0, Y0);
            permlane32_swap(X1, Y1);
            permlane16_swap(X1, Y1);
            union { uintx4 u; short8 s; } bu;
            bu.u[0] = X0; bu.u[1] = X1; bu.u[2] = Y0; bu.u[3] = Y1;
            short8 bfrag = bu.s;
            acc3[0][mt] = mfma16(af23_0, bfrag, acc3[0][mt]);
            acc3[1][mt] = mfma16(af23_1, bfrag, acc3[1][mt]);
            acc3[2][mt] = mfma16(af23_2, bfrag, acc3[2][mt]);
            acc3[3][mt] = mfma16(af23_3, bfrag, acc3[3][mt]);
        }
    }

    // ---- cross-wave k-reduction: 3-round round-robin via one 16KB buffer ----
    floatx4 fin[4];
    #pragma unroll
    for (int mt = 0; mt < 4; mt++) fin[mt] = acc3[0][mt];
    float* myslot = Red + dh * 1024;
    int lofs = lane * 4;
    // round 1
    #pragma unroll
    for (int mt = 0; mt < 4; mt++)
        *(floatx4*)(myslot + mt * 256 + lofs) = acc3[1][mt];
    __syncthreads();
    {
        const float* ps = Red + ((dh + 3) & 3) * 1024;
        #pragma unroll
        for (int mt = 0; mt < 4; mt++)
            fin[mt] += *(const floatx4*)(ps + mt * 256 + lofs);
    }
    __syncthreads();
    // round 2
    #pragma unroll
    for (int mt = 0; mt < 4; mt++)
        *(floatx4*)(myslot + mt * 256 + lofs) = acc3[2][mt];
    __syncthreads();
    {
        const float* ps = Red + ((dh + 2) & 3) * 1024;
        #pragma unroll
        for (int mt = 0; mt < 4; mt++)
            fin[mt] += *(const floatx4*)(ps + mt * 256 + lofs);
    }
    __syncthreads();
    // round 3
    #pragma unroll
    for (int mt = 0; mt < 4; mt++)
        *(floatx4*)(myslot + mt * 256 + lofs) = acc3[3][mt];
    __syncthreads();
    {
        const float* ps = Red + ((dh + 1) & 3) * 1024;
        #pragma unroll
        for (int mt = 0; mt < 4; mt++)
            fin[mt] += *(const floatx4*)(ps + mt * 256 + lofs);
    }

    // H overlays Ax (dead after nc loop; ordered by the reduce barriers)
    float* H = (float*)Ax;                   // [64 m][68] f32 = 17408 B
    int hb = dh * 16 + lgrp * 4;
    floatx4 b4 = *(const floatx4*)(bh1l + hb);
    #pragma unroll
    for (int mt = 0; mt < 4; mt++) {
        int m = mt * 16 + lane15;
        float gm = gats[m];
        floatx4 v;
        v[0] = fmaxf(fin[mt][0] * gm + b4[0], 0.f);
        v[1] = fmaxf(fin[mt][1] * gm + b4[1], 0.f);
        v[2] = fmaxf(fin[mt][2] * gm + b4[2], 0.f);
        v[3] = fmaxf(fin[mt][3] * gm + b4[3], 0.f);
        *(floatx4*)(H + m * 68 + hb) = v;
    }
    __syncthreads();                         // H complete

    int mloc = tid >> 2, c0 = (tid & 3) * 2;
    int tk = toks[mloc];
    float z0 = bh2l[c0], z1 = bh2l[c0 + 1];
    const floatx4* Hr4 = (const floatx4*)(H + mloc * 68);
    #pragma unroll
    for (int h4 = 0; h4 < 16; h4++) {
        floatx4 hv = Hr4[h4];
        #pragma unroll
        for (int r = 0; r < 4; r++) {
            int h = h4 * 4 + r;
            z0 += hv[r] * Wh2l[h * 8 + c0];
            z1 += hv[r] * Wh2l[h * 8 + c0 + 1];
        }
    }
    if (tk >= 0) {
        float2 rr;
        rr.x = __builtin_amdgcn_rcpf(1.0f + __expf(-z0));
        rr.y = __builtin_amdgcn_rcpf(1.0f + __expf(-z1));
        *(float2*)(result + (long)tk * 8 + c0) = rr;
    }

    // aux loss (block 0 only)
    if (bid == 0 && tid == 0) {
        const float Bf = 262144.0f;
        float tern = ternsum_g[0] * (1.0f / 1048576.0f);
        float sp = 0.f; float cp[4] = {0.f, 0.f, 0.f, 0.f};
        for (int tt = 0; tt < 16; tt++) {
            float frac = (float)cnt_g[tt] / Bf, mp = psum_g[tt] / Bf;
            sp += frac * mp; cp[tt >> 2] += mp;
        }
        float dv = 0.f;
        for (int cc = 0; cc < 4; cc++) dv += cp[cc] * logf(cp[cc] + 1e-9f);
        d_aux[0] = 0.01f * tern + 0.005f * (16.0f * sp) + 0.01f * dv;
    }
}

// ---------------- launch ----------------

extern "C" void kernel_launch(void* const* d_in, const int* in_sizes, int n_in,
                              void* d_out, int out_size, void* d_ws, size_t ws_size,
                              hipStream_t stream) {
    const int* op_idx = (const int*)d_in[0];
    const int* a_in   = (const int*)d_in[1];
    const int* b_in_i = (const int*)d_in[2];
    const int* c_in   = (const int*)d_in[3];
    const float* op_embed = (const float*)d_in[4];
    const float* W_in  = (const float*)d_in[5];
    const float* b_in  = (const float*)d_in[6];
    const float* Wr    = (const float*)d_in[7];
    const float* W1    = (const float*)d_in[8];
    const float* W2    = (const float*)d_in[9];
    const float* Wh1   = (const float*)d_in[10];
    const float* bh1   = (const float*)d_in[11];
    const float* Wh2   = (const float*)d_in[12];
    const float* bh2   = (const float*)d_in[13];

    const long B = in_sizes[0];  // 262144
    float* result = (float*)d_out;
    float* d_idx  = (float*)d_out + B * 8;
    float* d_aux  = (float*)d_out + B * 9;

    unsigned char* ws = (unsigned char*)d_ws;
    int*   bucket= (int*)(ws + 0);                                // 16 MB (16 x 262144 x 4B)
    unsigned short* W1qT  = (unsigned short*)(ws + 67108864);     // 2 MB
    unsigned short* W2qT  = (unsigned short*)(ws + 69206016);     // 2 MB
    unsigned short* W23qT = (unsigned short*)(ws + 71303168);     // 1 MB
    float* gate  = (float*)(ws + 72351744);                       // 1 MB
    float* Ta    = (float*)(ws + 74448896);                       // 128 KB
    float* Tb    = (float*)(ws + 74579968);                       // 128 KB
    float* embW  = (float*)(ws + 74711040);                       // 4 KB
    float* Tc    = (float*)(ws + 74715136);                       // 512 B
    float* TaR   = (float*)(ws + 74715648);                       // 16 KB
    float* TbR   = (float*)(ws + 74732032);                       // 16 KB
    float* embWr = (float*)(ws + 74748416);                       // 512 B
    float* TcR   = (float*)(ws + 74748928);                       // 64 B
    float* partials = (float*)(ws + 74748992);                    // 2 KB
    unsigned char* acc = ws + 74751040;
    float* ternsum = (float*)(acc + 0);
    float* psum    = (float*)(acc + 64);
    int*   cnt     = (int*)(acc + 128);
    int*   fill    = (int*)(acc + 192);

    hipMemsetAsync(acc, 0, 256, stream);

    k_prep1<<<773, 256, 0, stream>>>(W1, W2, partials, op_embed, W_in, b_in,
                                     embW, Ta, Tb, Tc);
    k_prep2<<<545, 256, 0, stream>>>(W1, W2, partials, W1qT, W2qT, ternsum,
                                     embW, Ta, Tb, Tc, Wr, embWr, TaR, TbR, TcR);
    k_main3<<<2048, 256, 0, stream>>>(op_idx, a_in, b_in_i, c_in,
                                      embWr, TaR, TbR, TcR,
                                      gate, psum, cnt, fill, bucket, d_idx,
                                      W2qT, Wh1, W23qT);
    k_ffn<<<4112, 256, 37664, stream>>>(op_idx, a_in, b_in_i, c_in,
                                        embW, Ta, Tb, Tc,
                                        gate, bucket, cnt, psum, ternsum,
                                        W1qT, W23qT, Wh2, bh1, bh2, result, d_aux);
}

// Round 7
// 246.690 us; speedup vs baseline: 1.2793x; 1.0238x over previous
//
#include <hip/hip_runtime.h>
#include <hip/hip_bf16.h>
#include <math.h>

typedef __attribute__((ext_vector_type(8))) short short8;
typedef __attribute__((ext_vector_type(4))) float floatx4;
typedef __attribute__((ext_vector_type(4))) unsigned int uintx4;

#define BUCKET_CAP 262144

__device__ __forceinline__ unsigned short f2bf(float f) {
    unsigned int u = __float_as_uint(f);
    unsigned int r = (u + 0x7fffu + ((u >> 16) & 1u)) >> 16;
    return (unsigned short)r;
}

// single-instruction RNE pack: low16 <- a, high16 <- b
__device__ __forceinline__ unsigned int cvtpk(float a, float b) {
    unsigned int r;
    asm("v_cvt_pk_bf16_f32 %0, %1, %2" : "=v"(r) : "v"(a), "v"(b));
    return r;
}

// swap a's upper 32 lanes with b's lower 32 lanes
__device__ __forceinline__ void permlane32_swap(unsigned int &a, unsigned int &b) {
    asm volatile("v_permlane32_swap_b32 %0, %1" : "+v"(a), "+v"(b));
}
// swap a's odd 16-lane groups with b's even 16-lane groups
__device__ __forceinline__ void permlane16_swap(unsigned int &a, unsigned int &b) {
    asm volatile("v_permlane16_swap_b32 %0, %1" : "+v"(a), "+v"(b));
}

// gelu(u) = u * sigmoid(1.5957691216*u*(1+0.044715*u^2))
// log2e folded: z = -(k1 + k3*u^2)*u, e = 2^z
__device__ __forceinline__ float gelu_f(float u) {
    float u2 = u * u;
    float p = __builtin_fmaf(u2, -0.102943242f, -2.302208184f);
    float z = p * u;
    float e;
    asm("v_exp_f32 %0, %1" : "=v"(e) : "v"(z));
    return u * __builtin_amdgcn_rcpf(1.0f + e);
}

__device__ __forceinline__ floatx4 mfma16(short8 a, short8 b, floatx4 c) {
    return __builtin_amdgcn_mfma_f32_16x16x32_bf16(a, b, c, 0, 0, 0);
}

// ---------------- Stage 1: |W| partial sums  ∪  input tables ----------------
// blocks [0,512): sumabs; blocks [512,773): tables

__global__ __launch_bounds__(256) void k_prep1(
        const float* __restrict__ W1, const float* __restrict__ W2,
        float* __restrict__ partials,
        const float* __restrict__ op_embed, const float* __restrict__ W_in,
        const float* __restrict__ b_in,
        float* embW, float* Ta, float* Tb, float* Tc) {
    __shared__ float red[256];
    int bid = blockIdx.x;
    if (bid < 512) {
        bool isW1 = bid < 256;
        const float* W = (isW1 ? W1 : W2) + (long)(isW1 ? bid : bid - 256) * 4096;
        float s = 0.f;
        #pragma unroll
        for (int i = 0; i < 4; i++) {
            floatx4 v = *(const floatx4*)(W + i * 1024 + threadIdx.x * 4);
            s += fabsf(v[0]) + fabsf(v[1]) + fabsf(v[2]) + fabsf(v[3]);
        }
        red[threadIdx.x] = s; __syncthreads();
        for (int st = 128; st > 0; st >>= 1) {
            if (threadIdx.x < st) red[threadIdx.x] += red[threadIdx.x + st];
            __syncthreads();
        }
        if (threadIdx.x == 0) partials[bid] = red[0];
    } else {
        int i = (bid - 512) * 256 + threadIdx.x;
        if (i < 1024) {
            int op = i >> 7, j = i & 127;
            float s = b_in[j];
            #pragma unroll
            for (int k = 0; k < 32; k++) s += op_embed[op * 32 + k] * W_in[k * 128 + j];
            embW[i] = s;
        } else if (i < 1024 + 32768) {
            int r = i - 1024; int a = r >> 7, j = r & 127;
            float s = 0.f;
            #pragma unroll
            for (int bit = 0; bit < 8; bit++) if ((a >> bit) & 1) s += W_in[(32 + bit) * 128 + j];
            Ta[r] = s;
        } else if (i < 33792 + 32768) {
            int r = i - 33792; int b = r >> 7, j = r & 127;
            float s = 0.f;
            #pragma unroll
            for (int bit = 0; bit < 8; bit++) if ((b >> bit) & 1) s += W_in[(40 + bit) * 128 + j];
            Tb[r] = s;
        } else if (i < 66560 + 128) {
            int j = i - 66560; Tc[j] = W_in[48 * 128 + j];
        }
    }
}

// ---------------- Stage 2: quantize  ∪  router tables ----------------
// blocks [0,512): quant (coalesced-output via LDS transpose); [512,545): tablesR

__global__ __launch_bounds__(256) void k_prep2(
        const float* __restrict__ W1, const float* __restrict__ W2,
        const float* __restrict__ partials,
        unsigned short* __restrict__ W1qT, unsigned short* __restrict__ W2qT,
        float* ternsum,
        const float* __restrict__ embW, const float* __restrict__ Ta,
        const float* __restrict__ Tb, const float* __restrict__ Tc,
        const float* __restrict__ Wr,
        float* embWr, float* TaR, float* TbR, float* TcR) {
    __shared__ unsigned short Lq[4096];
    __shared__ float red[256];
    int blk = blockIdx.x;
    if (blk >= 512) {
        int i = (blk - 512) * 256 + threadIdx.x;
        int row = i >> 4, t = i & 15;
        const float* src; float* dst;
        if (row < 8)        { src = embW + row * 128;        dst = embWr + i; }
        else if (row < 264) { src = Ta + (row - 8) * 128;    dst = TaR + (row - 8) * 16 + t; }
        else if (row < 520) { src = Tb + (row - 264) * 128;  dst = TbR + (row - 264) * 16 + t; }
        else if (row == 520){ src = Tc;                      dst = TcR + t; }
        else return;
        float s = 0.f;
        for (int j = 0; j < 128; j++) s += src[j] * Wr[j * 16 + t];
        *dst = s;
        return;
    }
    bool isW1 = blk < 256;
    int rb = isW1 ? blk : blk - 256;
    int t = rb >> 4, slab = rb & 15;
    const float* part = partials + (isW1 ? 0 : 256) + t * 16;
    float ssum = 0.f;
    #pragma unroll
    for (int i = 0; i < 16; i++) ssum += part[i];
    float s = ssum * (1.0f / 65536.0f);
    float thr = 0.7f * s;
    unsigned int us = (unsigned int)f2bf(s);   // bf16(+s); bf16(-s) = us|0x8000
    int tid = threadIdx.x;
    float dsum = 0.f;
    if (isW1) {
        // output W1qT[t] is [512 f][128 d]; slab = 32 f-rows. input W1[t] = [128 d][512 f]
        int f0 = slab * 32;
        int d = tid >> 1, fh = (tid & 1) * 16;
        const float* src = W1 + (long)t * 65536 + d * 512 + f0 + fh;
        #pragma unroll
        for (int i = 0; i < 4; i++) {
            floatx4 w = *(const floatx4*)(src + i * 4);
            #pragma unroll
            for (int r = 0; r < 4; r++) {
                float wv = w[r];
                float aw = fabsf(wv);
                bool big = aw > thr;
                dsum += big ? fabsf(aw - s) : aw;
                unsigned int sign15 = (__float_as_uint(wv) >> 16) & 0x8000u;
                unsigned short q = big ? (unsigned short)(us | sign15) : (unsigned short)0;
                Lq[(fh + i * 4 + r) * 128 + d] = q;   // [32 f][128 d]
            }
        }
    } else {
        // output W2qT[t] is [128 d][512 f]; slab = 8 d-rows. input W2[t] = [512 f][128 d]
        int d0 = slab * 8;
        int f = tid * 2;
        const float* src = W2 + (long)t * 65536 + f * 128 + d0;
        #pragma unroll
        for (int rr = 0; rr < 2; rr++) {
            #pragma unroll
            for (int i = 0; i < 2; i++) {
                floatx4 w = *(const floatx4*)(src + rr * 128 + i * 4);
                #pragma unroll
                for (int r = 0; r < 4; r++) {
                    float wv = w[r];
                    float aw = fabsf(wv);
                    bool big = aw > thr;
                    dsum += big ? fabsf(aw - s) : aw;
                    unsigned int sign15 = (__float_as_uint(wv) >> 16) & 0x8000u;
                    unsigned short q = big ? (unsigned short)(us | sign15) : (unsigned short)0;
                    Lq[(i * 4 + r) * 512 + f + rr] = q;   // [8 d][512 f]
                }
            }
        }
    }
    __syncthreads();
    unsigned short* dst = (isW1 ? W1qT : W2qT) + (long)t * 65536 + slab * 4096;
    const uintx4* Ls = (const uintx4*)Lq;
    uintx4* D4 = (uintx4*)dst;
    D4[tid] = Ls[tid];
    D4[tid + 256] = Ls[tid + 256];
    red[tid] = dsum; __syncthreads();
    for (int st2 = 128; st2 > 0; st2 >>= 1) {
        if (tid < st2) red[tid] += red[tid + st2];
        __syncthreads();
    }
    if (tid == 0) atomicAdd(ternsum, red[0]);
}

// ---------------- Stage 3: router front + fused scatter  ∪  W23 ----------------
// blocks [0,1024): router + bucket-scatter. Token mapping is BLOCK-CONTIGUOUS
// (tok = blockIdx*256 + e) so bucket entries are runs from one 256-token
// window -> k_ffn's gathers stay cache-line-local (R6 regression fix).
// Also packs (op,a,b,c,gate) into an 8B rec[tok] so k_ffn does ONE scattered
// load per token instead of five.
// blocks [1024,2048): w23

__global__ __launch_bounds__(256) void k_main3(
        const int* __restrict__ op_idx, const int* __restrict__ a_in,
        const int* __restrict__ b_in_i, const int* __restrict__ c_in,
        const float* __restrict__ embWr, const float* __restrict__ TaR,
        const float* __restrict__ TbR, const float* __restrict__ TcR,
        float2* __restrict__ rec_out,
        float* psum, int* cnt, int* fill, int* __restrict__ bucket,
        float* __restrict__ d_idx,
        const unsigned short* __restrict__ W2qT, const float* __restrict__ Wh1,
        unsigned short* __restrict__ W23qT) {
    __shared__ float sp[4][16];
    __shared__ int sc[4][16];
    __shared__ float wcol[128];
    __shared__ int lc[16], lbase[16];
    __shared__ unsigned char blE[256];   // bucket id per local token entry
    __shared__ unsigned char lpE[256];   // local pos per entry (<=255)

    if (blockIdx.x >= 1024) {
        int b2 = blockIdx.x - 1024;
        int t = b2 >> 6, h = b2 & 63;
        if (threadIdx.x < 128) wcol[threadIdx.x] = Wh1[threadIdx.x * 64 + h];
        __syncthreads();
        int k2 = threadIdx.x * 2;
        const unsigned short* w2 = W2qT + (long)t * 65536 + k2;
        float a0 = 0.f, a1 = 0.f;
        #pragma unroll 8
        for (int d = 0; d < 128; d++) {
            unsigned int u = *(const unsigned int*)(w2 + d * 512);
            float w = wcol[d];
            a0 += w * __uint_as_float(u << 16);
            a1 += w * __uint_as_float(u & 0xffff0000u);
        }
        *(unsigned int*)(W23qT + ((long)(t * 64 + h)) * 512 + k2) = cvtpk(a0, a1);
        return;
    }

    int tid = threadIdx.x;
    if (tid < 16) lc[tid] = 0;
    __syncthreads();

    int lane = tid & 63;
    int j = lane & 15;
    int grpbase = lane & 48;
    int tl = tid >> 4;                   // local token-group index (0..15)
    float psum_acc = 0.f; int cnt_acc = 0;

    #pragma unroll 1
    for (int it = 0; it < 16; it++) {
        int tok = blockIdx.x * 256 + it * 16 + tl;   // block-contiguous window
        int op = op_idx[tok], a = a_in[tok], b = b_in_i[tok], c = c_in[tok];
        float cf = (float)c;

        float lg = embWr[op * 16 + j] + TaR[a * 16 + j] + TbR[b * 16 + j] + cf * TcR[j];
        float m = lg;
        m = fmaxf(m, __shfl_xor(m, 8, 16));
        m = fmaxf(m, __shfl_xor(m, 4, 16));
        m = fmaxf(m, __shfl_xor(m, 2, 16));
        m = fmaxf(m, __shfl_xor(m, 1, 16));
        float p = __expf(lg - m);
        float s = p;
        s += __shfl_xor(s, 8, 16);
        s += __shfl_xor(s, 4, 16);
        s += __shfl_xor(s, 2, 16);
        s += __shfl_xor(s, 1, 16);
        float g = __builtin_amdgcn_rcpf(s);
        unsigned long long ball = __ballot(lg == m);
        int bi = __ffsll((unsigned long long)((ball >> grpbase) & 0xffffULL)) - 1;
        psum_acc += p * g;
        cnt_acc += (j == bi) ? 1 : 0;
        if (j == bi) {
            int lpos = atomicAdd(&lc[bi], 1);
            int e = it * 16 + tl;
            blE[e] = (unsigned char)bi;
            lpE[e] = (unsigned char)lpos;
        }
        if (j == 0) {
            unsigned int desc = (unsigned int)op | ((unsigned int)a << 3)
                              | ((unsigned int)b << 11) | ((unsigned int)c << 19);
            float2 rr; rr.x = __uint_as_float(desc); rr.y = g;
            rec_out[tok] = rr;
            d_idx[tok] = (float)bi;
        }
    }

    psum_acc += __shfl_xor(psum_acc, 16);
    psum_acc += __shfl_xor(psum_acc, 32);
    cnt_acc += __shfl_xor(cnt_acc, 16);
    cnt_acc += __shfl_xor(cnt_acc, 32);
    int wv = tid >> 6;
    if (lane < 16) { sp[wv][j] = psum_acc; sc[wv][j] = cnt_acc; }
    __syncthreads();
    if (tid < 16) {
        atomicAdd(&psum[tid], sp[0][tid] + sp[1][tid] + sp[2][tid] + sp[3][tid]);
        atomicAdd(&cnt[tid], sc[0][tid] + sc[1][tid] + sc[2][tid] + sc[3][tid]);
        lbase[tid] = atomicAdd(&fill[tid], lc[tid]);
    }
    __syncthreads();
    // finalize: each thread writes one token's bucket slot
    {
        int e = tid;
        int bi = (int)blE[e];
        int tok = blockIdx.x * 256 + e;
        bucket[bi * BUCKET_CAP + lbase[bi] + (int)lpE[e]] = tok;
    }
}

// ---------------- Phase C: MoE FFN + fused head ----------------
// x reconstructed IN-KERNEL from L2-resident tables (identical f32 math +
// cvtpk rounding -> bit-identical Ax; no xq buffer). Token metadata comes
// from ONE 8B rec[tok] load per token (desc-packed ints + gate).
// GEMM1 -> gelu -> in-register permute -> GEMM2 (k-split, rotated h-blocks)
// -> 16KB round-robin reduce -> H overlays Ax -> fused head.
// Inner loop: non-hoisted form (loads adjacent to consumers; R5's hoist
// regressed). launch_bounds(256,3): (256,4) spills (R3). VGPR+AGPR ~148/170.

__global__ __launch_bounds__(256, 3) void k_ffn(
    const float2* __restrict__ rec,
    const float* __restrict__ embW, const float* __restrict__ Ta,
    const float* __restrict__ Tb, const float* __restrict__ Tc,
    const int* __restrict__ bucket, const int* __restrict__ cnt_g,
    const float* __restrict__ psum_g, const float* __restrict__ ternsum_g,
    const unsigned short* __restrict__ W1qT, const unsigned short* __restrict__ W23qT,
    const float* __restrict__ Wh2, const float* __restrict__ bh1,
    const float* __restrict__ bh2,
    float* __restrict__ result, float* __restrict__ d_aux) {

    extern __shared__ __align__(16) unsigned char smem[];
    unsigned short* Ax = (unsigned short*)smem;            // [64][136] bf16 = 17408 B; H f32 [64][68] overlays
    float* Red = (float*)(smem + 17408);                   // 16384 B: 4 slots x [4 mt][64 lane][4]
    int*   toks = (int*)(smem + 33792);                    // 256 B
    float* gats = (float*)(smem + 34048);                  // 256 B
    float* Wh2l = (float*)(smem + 34304);                  // 2048 B
    float* bh2l = (float*)(smem + 36352);                  // 32 B
    float* bh1l = (float*)(smem + 36384);                  // 256 B
    int*   opsl = (int*)(smem + 36640);                    // 256 B
    int*   asl  = (int*)(smem + 36896);                    // 256 B
    int*   bsl  = (int*)(smem + 37152);                    // 256 B
    float* csl  = (float*)(smem + 37408);                  // 256 B (end 37664)

    int bid = blockIdx.x;
    // per-block uniform bid -> (tile, chunk) mapping from cnt
    int t = -1, ci = 0, nt = 0, base = 0;
    {
        int coff = 0;
        #pragma unroll 1
        for (int tt = 0; tt < 16; tt++) {
            int c = cnt_g[tt];
            int ch = (c + 63) >> 6;
            if (t < 0 && bid < coff + ch) {
                t = tt; ci = bid - coff; nt = c;
                base = tt * BUCKET_CAP + ci * 64;
            }
            coff += ch;
        }
    }
    if (t < 0) return;
    int nvalid = nt - ci * 64; if (nvalid > 64) nvalid = 64;

    int tid = threadIdx.x;
    if (tid < 64) {
        int tk = (tid < nvalid) ? bucket[base + tid] : -1;
        toks[tid] = tk;
        int tks = (tk >= 0) ? tk : 0;
        float2 rd = rec[tks];
        unsigned int desc = __float_as_uint(rd.x);
        gats[tid] = (tk >= 0) ? rd.y : 0.0f;   // gm=0 masks garbage rows
        opsl[tid] = (int)(desc & 7u);
        asl[tid]  = (int)((desc >> 3) & 255u);
        bsl[tid]  = (int)((desc >> 11) & 255u);
        csl[tid]  = (float)((desc >> 19) & 1u);
    }
    Wh2l[tid] = Wh2[tid];
    Wh2l[tid + 256] = Wh2[tid + 256];
    if (tid < 8) bh2l[tid] = bh2[tid];
    else if (tid < 72) bh1l[tid - 8] = bh1[tid - 8];
    __syncthreads();

    // stage x rows: reconstruct from tables (L2-resident), identical rounding
    #pragma unroll
    for (int it = 0; it < 4; it++) {
        int seg = it * 256 + tid; int r = seg >> 4, sg = seg & 15;
        int d0 = sg * 8;
        int op = opsl[r], a = asl[r], b = bsl[r];
        float cf = csl[r];
        const floatx4* Ev = (const floatx4*)(embW + op * 128 + d0);
        const floatx4* A4 = (const floatx4*)(Ta + a * 128 + d0);
        const floatx4* B4 = (const floatx4*)(Tb + b * 128 + d0);
        const floatx4* C4 = (const floatx4*)(Tc + d0);
        floatx4 v0 = Ev[0] + A4[0] + B4[0] + cf * C4[0];
        floatx4 v1 = Ev[1] + A4[1] + B4[1] + cf * C4[1];
        uintx4 o;
        o[0] = cvtpk(v0[0], v0[1]);
        o[1] = cvtpk(v0[2], v0[3]);
        o[2] = cvtpk(v1[0], v1[1]);
        o[3] = cvtpk(v1[2], v1[3]);
        *(uintx4*)(Ax + r * 136 + sg * 8) = o;
    }
    __syncthreads();

    int lane = tid & 63, dh = tid >> 6;
    int lane15 = lane & 15, lgrp = lane >> 4;

    floatx4 acc3[4][4];   // [i][mt]; i-th slot = h-block (dh+i)&3 (rotated order)
    #pragma unroll
    for (int i = 0; i < 4; i++)
        #pragma unroll
        for (int j = 0; j < 4; j++) acc3[i][j] = (floatx4){0.f, 0.f, 0.f, 0.f};

    const unsigned short* w1p  = W1qT + (long)t * 65536 + (dh * 32 + lane15) * 128 + lgrp * 8;
    const unsigned short* w23p = W23qT + (long)t * 32768 + lane15 * 512 + dh * 32 + lgrp * 8;
    int ho0 = dh * 8192;
    int ho1 = ((dh + 1) & 3) * 8192;
    int ho2 = ((dh + 2) & 3) * 8192;
    int ho3 = ((dh + 3) & 3) * 8192;

    for (int nc = 0; nc < 4; nc++) {
        // GEMM1: A = W1 rows (global), B = Ax (LDS)
        floatx4 acc1[2][4];
        #pragma unroll
        for (int i = 0; i < 2; i++)
            #pragma unroll
            for (int j = 0; j < 4; j++) acc1[i][j] = (floatx4){0.f, 0.f, 0.f, 0.f};

        const unsigned short* w1c = w1p + nc * 16384;
        #pragma unroll
        for (int kk = 0; kk < 4; kk++) {
            short8 af0 = *(const short8*)(w1c + kk * 32);
            short8 af1 = *(const short8*)(w1c + 2048 + kk * 32);
            int ko = kk * 32 + lgrp * 8;
            #pragma unroll
            for (int mt = 0; mt < 4; mt++) {
                short8 bf = *(const short8*)(Ax + (mt * 16 + lane15) * 136 + ko);
                acc1[0][mt] = mfma16(af0, bf, acc1[0][mt]);
                acc1[1][mt] = mfma16(af1, bf, acc1[1][mt]);
            }
        }

        // A-fragments for GEMM2, rotated h-block order
        const unsigned short* w23c = w23p + nc * 128;
        short8 af23_0 = *(const short8*)(w23c + ho0);
        short8 af23_1 = *(const short8*)(w23c + ho1);
        short8 af23_2 = *(const short8*)(w23c + ho2);
        short8 af23_3 = *(const short8*)(w23c + ho3);

        // fuse: gelu -> cvtpk -> lane permute -> B-fragment -> 4 MFMAs (per mt)
        #pragma unroll
        for (int mt = 0; mt < 4; mt++) {
            floatx4 v0 = acc1[0][mt], v1 = acc1[1][mt];
            unsigned int X0 = cvtpk(gelu_f(v0[0]), gelu_f(v0[1]));
            unsigned int X1 = cvtpk(gelu_f(v0[2]), gelu_f(v0[3]));
            unsigned int Y0 = cvtpk(gelu_f(v1[0]), gelu_f(v1[1]));
            unsigned int Y1 = cvtpk(gelu_f(v1[2]), gelu_f(v1[3]));
            permlane32_swap(X0, Y0);
            permlane16_swap(X0, Y0);
            permlane32_swap(X1, Y1);
            permlane16_swap(X1, Y1);
            union { uintx4 u; short8 s; } bu;
            bu.u[0] = X0; bu.u[1] = X1; bu.u[2] = Y0; bu.u[3] = Y1;
            short8 bfrag = bu.s;
            acc3[0][mt] = mfma16(af23_0, bfrag, acc3[0][mt]);
            acc3[1][mt] = mfma16(af23_1, bfrag, acc3[1][mt]);
            acc3[2][mt] = mfma16(af23_2, bfrag, acc3[2][mt]);
            acc3[3][mt] = mfma16(af23_3, bfrag, acc3[3][mt]);
        }
    }

    // ---- cross-wave k-reduction: 3-round round-robin via one 16KB buffer ----
    floatx4 fin[4];
    #pragma unroll
    for (int mt = 0; mt < 4; mt++) fin[mt] = acc3[0][mt];
    float* myslot = Red + dh * 1024;
    int lofs = lane * 4;
    // round 1
    #pragma unroll
    for (int mt = 0; mt < 4; mt++)
        *(floatx4*)(myslot + mt * 256 + lofs) = acc3[1][mt];
    __syncthreads();
    {
        const float* ps = Red + ((dh + 3) & 3) * 1024;
        #pragma unroll
        for (int mt = 0; mt < 4; mt++)
            fin[mt] += *(const floatx4*)(ps + mt * 256 + lofs);
    }
    __syncthreads();
    // round 2
    #pragma unroll
    for (int mt = 0; mt < 4; mt++)
        *(floatx4*)(myslot + mt * 256 + lofs) = acc3[2][mt];
    __syncthreads();
    {
        const float* ps = Red + ((dh + 2) & 3) * 1024;
        #pragma unroll
        for (int mt = 0; mt < 4; mt++)
            fin[mt] += *(const floatx4*)(ps + mt * 256 + lofs);
    }
    __syncthreads();
    // round 3
    #pragma unroll
    for (int mt = 0; mt < 4; mt++)
        *(floatx4*)(myslot + mt * 256 + lofs) = acc3[3][mt];
    __syncthreads();
    {
        const float* ps = Red + ((dh + 1) & 3) * 1024;
        #pragma unroll
        for (int mt = 0; mt < 4; mt++)
            fin[mt] += *(const floatx4*)(ps + mt * 256 + lofs);
    }

    // H overlays Ax (dead after nc loop; ordered by the reduce barriers)
    float* H = (float*)Ax;                   // [64 m][68] f32 = 17408 B
    int hb = dh * 16 + lgrp * 4;
    floatx4 b4 = *(const floatx4*)(bh1l + hb);
    #pragma unroll
    for (int mt = 0; mt < 4; mt++) {
        int m = mt * 16 + lane15;
        float gm = gats[m];
        floatx4 v;
        v[0] = fmaxf(fin[mt][0] * gm + b4[0], 0.f);
        v[1] = fmaxf(fin[mt][1] * gm + b4[1], 0.f);
        v[2] = fmaxf(fin[mt][2] * gm + b4[2], 0.f);
        v[3] = fmaxf(fin[mt][3] * gm + b4[3], 0.f);
        *(floatx4*)(H + m * 68 + hb) = v;
    }
    __syncthreads();                         // H complete

    int mloc = tid >> 2, c0 = (tid & 3) * 2;
    int tk = toks[mloc];
    float z0 = bh2l[c0], z1 = bh2l[c0 + 1];
    const floatx4* Hr4 = (const floatx4*)(H + mloc * 68);
    #pragma unroll
    for (int h4 = 0; h4 < 16; h4++) {
        floatx4 hv = Hr4[h4];
        #pragma unroll
        for (int r = 0; r < 4; r++) {
            int h = h4 * 4 + r;
            z0 += hv[r] * Wh2l[h * 8 + c0];
            z1 += hv[r] * Wh2l[h * 8 + c0 + 1];
        }
    }
    if (tk >= 0) {
        float2 rr;
        rr.x = __builtin_amdgcn_rcpf(1.0f + __expf(-z0));
        rr.y = __builtin_amdgcn_rcpf(1.0f + __expf(-z1));
        *(float2*)(result + (long)tk * 8 + c0) = rr;
    }

    // aux loss (block 0 only)
    if (bid == 0 && tid == 0) {
        const float Bf = 262144.0f;
        float tern = ternsum_g[0] * (1.0f / 1048576.0f);
        float sp = 0.f; float cp[4] = {0.f, 0.f, 0.f, 0.f};
        for (int tt = 0; tt < 16; tt++) {
            float frac = (float)cnt_g[tt] / Bf, mp = psum_g[tt] / Bf;
            sp += frac * mp; cp[tt >> 2] += mp;
        }
        float dv = 0.f;
        for (int cc = 0; cc < 4; cc++) dv += cp[cc] * logf(cp[cc] + 1e-9f);
        d_aux[0] = 0.01f * tern + 0.005f * (16.0f * sp) + 0.01f * dv;
    }
}

// ---------------- launch ----------------

extern "C" void kernel_launch(void* const* d_in, const int* in_sizes, int n_in,
                              void* d_out, int out_size, void* d_ws, size_t ws_size,
                              hipStream_t stream) {
    const int* op_idx = (const int*)d_in[0];
    const int* a_in   = (const int*)d_in[1];
    const int* b_in_i = (const int*)d_in[2];
    const int* c_in   = (const int*)d_in[3];
    const float* op_embed = (const float*)d_in[4];
    const float* W_in  = (const float*)d_in[5];
    const float* b_in  = (const float*)d_in[6];
    const float* Wr    = (const float*)d_in[7];
    const float* W1    = (const float*)d_in[8];
    const float* W2    = (const float*)d_in[9];
    const float* Wh1   = (const float*)d_in[10];
    const float* bh1   = (const float*)d_in[11];
    const float* Wh2   = (const float*)d_in[12];
    const float* bh2   = (const float*)d_in[13];

    const long B = in_sizes[0];  // 262144
    float* result = (float*)d_out;
    float* d_idx  = (float*)d_out + B * 8;
    float* d_aux  = (float*)d_out + B * 9;

    unsigned char* ws = (unsigned char*)d_ws;
    int*   bucket= (int*)(ws + 0);                                // 16 MB (16 x 262144 x 4B)
    unsigned short* W1qT  = (unsigned short*)(ws + 67108864);     // 2 MB
    unsigned short* W2qT  = (unsigned short*)(ws + 69206016);     // 2 MB
    unsigned short* W23qT = (unsigned short*)(ws + 71303168);     // 1 MB
    float2* rec  = (float2*)(ws + 72351744);                      // 2 MB
    float* Ta    = (float*)(ws + 74448896);                       // 128 KB
    float* Tb    = (float*)(ws + 74579968);                       // 128 KB
    float* embW  = (float*)(ws + 74711040);                       // 4 KB
    float* Tc    = (float*)(ws + 74715136);                       // 512 B
    float* TaR   = (float*)(ws + 74715648);                       // 16 KB
    float* TbR   = (float*)(ws + 74732032);                       // 16 KB
    float* embWr = (float*)(ws + 74748416);                       // 512 B
    float* TcR   = (float*)(ws + 74748928);                       // 64 B
    float* partials = (float*)(ws + 74748992);                    // 2 KB
    unsigned char* acc = ws + 74751040;
    float* ternsum = (float*)(acc + 0);
    float* psum    = (float*)(acc + 64);
    int*   cnt     = (int*)(acc + 128);
    int*   fill    = (int*)(acc + 192);

    hipMemsetAsync(acc, 0, 256, stream);

    k_prep1<<<773, 256, 0, stream>>>(W1, W2, partials, op_embed, W_in, b_in,
                                     embW, Ta, Tb, Tc);
    k_prep2<<<545, 256, 0, stream>>>(W1, W2, partials, W1qT, W2qT, ternsum,
                                     embW, Ta, Tb, Tc, Wr, embWr, TaR, TbR, TcR);
    k_main3<<<2048, 256, 0, stream>>>(op_idx, a_in, b_in_i, c_in,
                                      embWr, TaR, TbR, TcR,
                                      rec, psum, cnt, fill, bucket, d_idx,
                                      W2qT, Wh1, W23qT);
    k_ffn<<<4112, 256, 37664, stream>>>(rec,
                                        embW, Ta, Tb, Tc,
                                        bucket, cnt, psum, ternsum,
                                        W1qT, W23qT, Wh2, bh1, bh2, result, d_aux);
}